// Round 1
// baseline (1220.855 us; speedup 1.0000x reference)
//
#include <hip/hip_runtime.h>
#include <cstddef>

#define NN 8192
#define FD 768
#define HIDD 384
#define NNZE 131072
#define DCATD 1536

typedef short bf16x8 __attribute__((ext_vector_type(8)));
typedef float f32x4 __attribute__((ext_vector_type(4)));

__device__ __forceinline__ short f2bf(float f){
  unsigned u = __float_as_uint(f);
  unsigned r = u + 0x7FFFu + ((u>>16)&1u);   // RNE
  return (short)(r>>16);
}
__device__ __forceinline__ float bf2f(short s){
  return __uint_as_float(((unsigned)(unsigned short)s)<<16);
}

// async global -> LDS, 16B per lane. lds ptr wave-uniform; HW scatters lane*16.
__device__ __forceinline__ void async_copy16(void* lds, const void* g){
  __builtin_amdgcn_global_load_lds((__attribute__((address_space(1))) void*)g,
                                   (__attribute__((address_space(3))) void*)lds, 16, 0, 0);
}

// ---------------- CSR build ----------------
__global__ void k_hist(const int* __restrict__ row, const int* __restrict__ col,
                       int* __restrict__ cr, int* __restrict__ cc){
  int e = blockIdx.x*256 + threadIdx.x;
  if(e >= NNZE) return;
  atomicAdd(&cc[col[e]], 1);
  atomicAdd(&cr[row[e]], 1);
}

// 2 blocks: block 0 scans col counts (-> col_off/cur + Bn), block 1 row (-> row_off/cur + Dn)
__global__ __launch_bounds__(1024) void k_scan2(const int* __restrict__ cnt_col,
    const int* __restrict__ cnt_row,
    int* __restrict__ col_off, int* __restrict__ row_off,
    int* __restrict__ col_cur, int* __restrict__ row_cur,
    float* __restrict__ Bn, float* __restrict__ Dn){
  const int* cnt = (blockIdx.x==0) ? cnt_col : cnt_row;
  int* offs = (blockIdx.x==0) ? col_off : row_off;
  int* cur  = (blockIdx.x==0) ? col_cur : row_cur;
  float* rec= (blockIdx.x==0) ? Bn : Dn;
  __shared__ int part[1024];
  int t = threadIdx.x;
  int v[8]; int s = 0;
  #pragma unroll
  for(int j=0;j<8;j++){ v[j]=cnt[t*8+j]; s+=v[j]; }
  part[t]=s; __syncthreads();
  for(int d=1; d<1024; d<<=1){
    int mine = part[t];
    int add = (t>=d)? part[t-d] : 0;
    __syncthreads();
    part[t] = mine + add;
    __syncthreads();
  }
  int excl = part[t]-s;
  #pragma unroll
  for(int j=0;j<8;j++){
    offs[t*8+j]=excl; cur[t*8+j]=excl; excl+=v[j];
    rec[t*8+j] = (v[j]>0) ? 1.f/(float)v[j] : 0.f;
  }
  if(t==1023) offs[8192]=excl;
}

__global__ void k_scatter(const int* __restrict__ row, const int* __restrict__ col,
                          int* __restrict__ ccur, int* __restrict__ rcur,
                          int* __restrict__ ceids, int* __restrict__ reids){
  int e = blockIdx.x*256 + threadIdx.x;
  if(e >= NNZE) return;
  int p = atomicAdd(&ccur[col[e]],1); ceids[p]=e;
  int q = atomicAdd(&rcur[row[e]],1); reids[q]=e;
}

// ---------------- all weight casts in ONE dispatch ----------------
// blocks [0,nW1): W1 (2048 elems each); then 288 hg1W, 288 hg2W, 144 fc1W, 144 fc2W
__global__ __launch_bounds__(256) void k_cvt_all(int nW1,
    const float* __restrict__ W1, short* __restrict__ W1b,
    const float* __restrict__ hg1W, short* __restrict__ wb1,
    const float* __restrict__ hg2W, short* __restrict__ wb2,
    const float* __restrict__ fc1W, short* __restrict__ fwb1,
    const float* __restrict__ fc2W, short* __restrict__ fwb2){
  int b = blockIdx.x;
  const float* s; short* d; size_t base;
  if(b < nW1){ s=W1; d=W1b; base=(size_t)b*2048; }
  else {
    int r = b - nW1;
    if(r<288){ s=hg1W; d=wb1; base=(size_t)r*2048; }
    else if(r<576){ s=hg2W; d=wb2; base=(size_t)(r-288)*2048; }
    else if(r<720){ s=fc1W; d=fwb1; base=(size_t)(r-576)*2048; }
    else { s=fc2W; d=fwb2; base=(size_t)(r-720)*2048; }
  }
  size_t i = base + (size_t)threadIdx.x*8;
  float4 f0 = *(const float4*)(s+i);
  float4 f1 = *(const float4*)(s+i+4);
  bf16x8 t;
  t[0]=f2bf(f0.x); t[1]=f2bf(f0.y); t[2]=f2bf(f0.z); t[3]=f2bf(f0.w);
  t[4]=f2bf(f1.x); t[5]=f2bf(f1.y); t[6]=f2bf(f1.z); t[7]=f2bf(f1.w);
  *(bf16x8*)(d+i) = t;
}

// ---------------- GraphNorm stats ----------------
__global__ __launch_bounds__(256) void k_colstats(const float* __restrict__ src,
                                                  float* __restrict__ gs, float* __restrict__ gss){
  int col = blockIdx.x*256 + threadIdx.x;     // 0..767
  int r0 = blockIdx.y*256;
  float s1=0.f, s2=0.f;
  for(int r=0;r<256;r++){
    float v = src[(size_t)(r0+r)*FD + col];
    s1+=v; s2+=v*v;
  }
  atomicAdd(&gs[col], s1);
  atomicAdd(&gss[col], s2);
}

// per-column: W^T·att dots  +  GraphNorm affine coeffs (gn_fin fused)
__global__ __launch_bounds__(256) void k_watt(const float* __restrict__ W, const float* __restrict__ att,
    const float* __restrict__ gs, const float* __restrict__ gss,
    const float* __restrict__ w_, const float* __restrict__ b_, const float* __restrict__ ms_,
    float* __restrict__ gnA, float* __restrict__ gnB,
    float* __restrict__ wxr, float* __restrict__ we){
  int c = blockIdx.x; int t = threadIdx.x;
  float sA=0.f, sB=0.f;
  for(int f=t; f<FD; f+=256){
    float w = W[(size_t)f*FD + c];
    sA += w*att[f];
    sB += w*att[FD+f];
  }
  __shared__ float shA[256], shB[256];
  shA[t]=sA; shB[t]=sB; __syncthreads();
  for(int s=128;s>0;s>>=1){ if(t<s){ shA[t]+=shA[t+s]; shB[t]+=shB[t+s]; } __syncthreads(); }
  if(t==0){
    float mean = gs[c]*(1.f/(float)NN);
    float ex2  = gss[c]*(1.f/(float)NN);
    float ctr  = ms_[c]*mean;
    float var  = ex2 - 2.f*ctr*mean + ctr*ctr;
    float a    = w_[c] / sqrtf(var + 1e-5f);
    gnA[c]=a; gnB[c]=b_[c] - a*ctr;
    wxr[c]=shA[0]; we[c]=shB[0];
  }
}

// a[i] = sum_c src[i,c]*wv[c]   (a_e path)
__global__ __launch_bounds__(64) void k_matvec(const float* __restrict__ src, const float* __restrict__ wv,
    float* __restrict__ out){
  int i = blockIdx.x, l = threadIdx.x;
  float s=0.f;
  for(int c=l;c<FD;c+=64) s += src[(size_t)i*FD+c]*wv[c];
  for(int o=32;o;o>>=1) s += __shfl_down(s,o);
  if(l==0) out[i] = s;
}

// normalized bf16 row + dot with wxr in one pass (affcast + matvec a_x fused)
__global__ __launch_bounds__(256) void k_affdot(const float* __restrict__ src,
    const float* __restrict__ A, const float* __restrict__ B, const float* __restrict__ wxr,
    short* __restrict__ dstb, float* __restrict__ ax){
  int i = blockIdx.x, t = threadIdx.x;
  float p = 0.f;
  #pragma unroll
  for(int k=0;k<3;k++){
    int c = t + k*256;
    float v = A[c]*src[(size_t)i*FD+c] + B[c];
    dstb[(size_t)i*FD+c] = f2bf(v);
    p += v*wxr[c];
  }
  __shared__ float sh[256];
  sh[t]=p; __syncthreads();
  for(int s=128;s>0;s>>=1){ if(t<s) sh[t]+=sh[t+s]; __syncthreads(); }
  if(t==0) ax[i]=sh[0];
}

// ---------------- m97-style LDS-staged bf16 NT GEMM (BK=32) ----------------
// C (f32) and/or Cb (bf16) outputs; either may be null.
__global__ __launch_bounds__(256) void gemm_lds(const short* __restrict__ A, const short* __restrict__ B,
    float* __restrict__ C, short* __restrict__ Cb, int M, int N, int K,
    const float* __restrict__ bias, float slope){
  __shared__ __align__(16) short As[128*32];
  __shared__ __align__(16) short Bs[128*32];
  int t = threadIdx.x;
  int w = t>>6, l = t&63;
  int m0 = blockIdx.y*128, n0 = blockIdx.x*128;
  int wm = w>>1, wn = w&1;
  int li = l&15, q = l>>4;
  const short* Ag = A + (size_t)(m0 + w*16 + (l>>2))*K + (l&3)*8;
  const short* Bg = B + (size_t)(n0 + w*16 + (l>>2))*K + (l&3)*8;
  short* Asl = &As[(w*16)*32];
  short* Bsl = &Bs[(w*16)*32];
  f32x4 acc[4][4];
  #pragma unroll
  for(int i=0;i<4;i++)
    #pragma unroll
    for(int j=0;j<4;j++) acc[i][j] = (f32x4){0.f,0.f,0.f,0.f};
  for(int k0=0;k0<K;k0+=32){
    async_copy16(Asl,          Ag + k0);
    async_copy16(Asl + 64*32,  Ag + (size_t)64*K + k0);
    async_copy16(Bsl,          Bg + k0);
    async_copy16(Bsl + 64*32,  Bg + (size_t)64*K + k0);
    __syncthreads();
    bf16x8 a[4], b[4];
    #pragma unroll
    for(int i=0;i<4;i++) a[i] = *(const bf16x8*)&As[(wm*64 + i*16 + li)*32 + q*8];
    #pragma unroll
    for(int j=0;j<4;j++) b[j] = *(const bf16x8*)&Bs[(wn*64 + j*16 + li)*32 + q*8];
    #pragma unroll
    for(int i=0;i<4;i++)
      #pragma unroll
      for(int j=0;j<4;j++)
        acc[i][j] = __builtin_amdgcn_mfma_f32_16x16x32_bf16(a[i], b[j], acc[i][j], 0, 0, 0);
    __syncthreads();
  }
  #pragma unroll
  for(int i=0;i<4;i++){
    int gm = m0 + wm*64 + i*16 + q*4;
    #pragma unroll
    for(int j=0;j<4;j++){
      int gn = n0 + wn*64 + j*16 + li;
      float bv = bias ? bias[gn] : 0.f;
      #pragma unroll
      for(int r=0;r<4;r++){
        float vv = acc[i][j][r] + bv;
        vv = (vv>=0.f) ? vv : vv*slope;
        if(C)  C[(size_t)(gm+r)*N + gn] = vv;
        if(Cb) Cb[(size_t)(gm+r)*N + gn] = f2bf(vv);
      }
    }
  }
}

// ---------------- per-segment softmax via CSR ----------------
__global__ __launch_bounds__(256) void k_softmax_seg(const int* __restrict__ offs,
    const int* __restrict__ eids, const int* __restrict__ row,
    const float* __restrict__ ax, const float* __restrict__ ae, float* __restrict__ asm_){
  int seg = blockIdx.x*4 + (threadIdx.x>>6);
  int l = threadIdx.x & 63;
  int beg = offs[seg], end = offs[seg+1];
  if(beg >= end) return;                 // wave-uniform
  float aev = ae[seg];
  float m = -1e30f;
  for(int idx=beg+l; idx<end; idx+=64){
    int e = eids[idx];
    float a = ax[row[e]] + aev; a = (a>=0.f)?a:0.2f*a;
    m = fmaxf(m, a);
  }
  #pragma unroll
  for(int o=1;o<64;o<<=1) m = fmaxf(m, __shfl_xor(m,o));
  float s = 0.f;
  for(int idx=beg+l; idx<end; idx+=64){
    int e = eids[idx];
    float a = ax[row[e]] + aev; a = (a>=0.f)?a:0.2f*a;
    s += expf(a-m);
  }
  #pragma unroll
  for(int o=1;o<64;o<<=1) s += __shfl_xor(s,o);
  float inv = 1.f/(s + 1e-16f);
  for(int idx=beg+l; idx<end; idx+=64){
    int e = eids[idx];
    float a = ax[row[e]] + aev; a = (a>=0.f)?a:0.2f*a;
    asm_[e] = expf(a-m)*inv;
  }
}

// ---------------- segment gather-sum, bf16 source (halved read traffic) ------------
// src rows are bf16; optional f32 dst and/or bf16 dstb outputs.
__global__ __launch_bounds__(192) void k_seg_gather(const short* __restrict__ srcb,
    const int* __restrict__ offs, const int* __restrict__ eids,
    const int* __restrict__ gidx, const float* __restrict__ alpha_sm,
    const float* __restrict__ segscale, const float* __restrict__ bias, float slope,
    float* __restrict__ dst, short* __restrict__ dstb){
  int c = blockIdx.x, t = threadIdx.x;   // t in [0,192), 4 cols each
  int beg = offs[c], end = offs[c+1];
  float scale = segscale[c];
  __shared__ float wsh[192]; __shared__ int rsh[192];
  float4 acc = {0.f,0.f,0.f,0.f};
  for(int base=beg; base<end; base+=192){
    int idx = base+t;
    if(idx<end){ int e=eids[idx]; wsh[t]=alpha_sm[e]; rsh[t]=gidx[e]; }
    __syncthreads();
    int cnt = min(192, end-base);
    int j=0;
    for(; j+1<cnt; j+=2){
      float w0=wsh[j], w1=wsh[j+1];
      short4 s0 = *((const short4*)(srcb + (size_t)rsh[j]*FD) + t);
      short4 s1 = *((const short4*)(srcb + (size_t)rsh[j+1]*FD) + t);
      acc.x += w0*bf2f(s0.x) + w1*bf2f(s1.x);
      acc.y += w0*bf2f(s0.y) + w1*bf2f(s1.y);
      acc.z += w0*bf2f(s0.z) + w1*bf2f(s1.z);
      acc.w += w0*bf2f(s0.w) + w1*bf2f(s1.w);
    }
    if(j<cnt){
      float w0=wsh[j];
      short4 s0 = *((const short4*)(srcb + (size_t)rsh[j]*FD) + t);
      acc.x += w0*bf2f(s0.x); acc.y += w0*bf2f(s0.y);
      acc.z += w0*bf2f(s0.z); acc.w += w0*bf2f(s0.w);
    }
    __syncthreads();
  }
  acc.x*=scale; acc.y*=scale; acc.z*=scale; acc.w*=scale;
  if(bias){
    float4 bv = *((const float4*)bias + t);
    acc.x+=bv.x; acc.y+=bv.y; acc.z+=bv.z; acc.w+=bv.w;
    acc.x=(acc.x>=0.f)?acc.x:slope*acc.x;
    acc.y=(acc.y>=0.f)?acc.y:slope*acc.y;
    acc.z=(acc.z>=0.f)?acc.z:slope*acc.z;
    acc.w=(acc.w>=0.f)?acc.w:slope*acc.w;
  }
  if(dst) *((float4*)(dst + (size_t)c*FD) + t) = acc;
  if(dstb){
    short4 o; o.x=f2bf(acc.x); o.y=f2bf(acc.y); o.z=f2bf(acc.z); o.w=f2bf(acc.w);
    *((short4*)(dstb + (size_t)c*FD) + t) = o;
  }
}

// ---------------- catT build ----------------
__global__ __launch_bounds__(256) void k_build_catT(const float* __restrict__ x,
    const float* __restrict__ o1, const float* __restrict__ o2, short* __restrict__ catT){
  __shared__ float tile[32][33];
  int i0 = blockIdx.x*32, d0 = blockIdx.y*32;
  int tx = threadIdx.x, ty = threadIdx.y;   // 32 x 8
  const float* src; int dof, ld;
  if(d0 < FD){ src=x; dof=d0; ld=FD; }
  else if(d0 < FD+HIDD){ src=o1; dof=d0-FD; ld=HIDD; }
  else { src=o2; dof=d0-FD-HIDD; ld=HIDD; }
  for(int yy=ty; yy<32; yy+=8)
    tile[yy][tx] = src[(size_t)(i0+yy)*ld + dof + tx];
  __syncthreads();
  for(int yy=ty; yy<32; yy+=8)
    catT[(size_t)(d0+yy)*NN + i0 + tx] = f2bf(tile[tx][yy]);
}

// ---------------- attention mega-GEMM (m97 LDS structure, BK=64: two 32-panels) ------
// BK=64 halves the barrier-pair count (2-phase critical path = stage+vmcnt+barrier, m233).
// LDS kept as two side-by-side [128][32] panels so staging/ds_read bank behavior is
// identical to the proven BK=32 pattern (avoids 16-way conflicts of a flat [128][64]).
__global__ __launch_bounds__(256) void attn_gemm_lds(const short* __restrict__ catT,
    const short* __restrict__ W1b, const float* __restrict__ b1, const float* __restrict__ W2,
    float* __restrict__ score_pre){
  const int K = NN;
  __shared__ __align__(16) short As[2*128*32];
  __shared__ __align__(16) short Bs[2*128*32];
  int id = blockIdx.x;             // 0..767
  int cc = id&7, g = id>>3;
  int m_idx = g%12;
  int n_idx = (g/12)*8 + cc;
  int m0 = m_idx*128, n0 = n_idx*128;
  int t = threadIdx.x;
  int w = t>>6, l = t&63;
  int wm = w>>1, wn = w&1;
  int li = l&15, q = l>>4;
  const short* Ag = catT + (size_t)(m0 + w*16 + (l>>2))*K + (l&3)*8;
  const short* Bg = W1b + (size_t)(n0 + w*16 + (l>>2))*K + (l&3)*8;
  short* Asl = &As[(w*16)*32];
  short* Bsl = &Bs[(w*16)*32];
  f32x4 acc[4][4];
  #pragma unroll
  for(int i=0;i<4;i++)
    #pragma unroll
    for(int j=0;j<4;j++) acc[i][j] = (f32x4){0.f,0.f,0.f,0.f};
  for(int k0=0;k0<K;k0+=64){
    // panel kk=0: cols [k0,k0+32); panel kk=1: cols [k0+32,k0+64)
    async_copy16(Asl,            Ag + k0);
    async_copy16(Asl + 64*32,    Ag + (size_t)64*K + k0);
    async_copy16(Asl + 128*32,   Ag + k0 + 32);
    async_copy16(Asl + 192*32,   Ag + (size_t)64*K + k0 + 32);
    async_copy16(Bsl,            Bg + k0);
    async_copy16(Bsl + 64*32,    Bg + (size_t)64*K + k0);
    async_copy16(Bsl + 128*32,   Bg + k0 + 32);
    async_copy16(Bsl + 192*32,   Bg + (size_t)64*K + k0 + 32);
    __syncthreads();
    #pragma unroll
    for(int kk=0;kk<2;kk++){
      bf16x8 a[4], b[4];
      #pragma unroll
      for(int i=0;i<4;i++) a[i] = *(const bf16x8*)&As[kk*4096 + (wm*64 + i*16 + li)*32 + q*8];
      #pragma unroll
      for(int j=0;j<4;j++) b[j] = *(const bf16x8*)&Bs[kk*4096 + (wn*64 + j*16 + li)*32 + q*8];
      #pragma unroll
      for(int i=0;i<4;i++)
        #pragma unroll
        for(int j=0;j<4;j++)
          acc[i][j] = __builtin_amdgcn_mfma_f32_16x16x32_bf16(a[i], b[j], acc[i][j], 0, 0, 0);
    }
    __syncthreads();
  }
  float w2v[4], b1v[4];
  #pragma unroll
  for(int j=0;j<4;j++){ int gn = n0 + wn*64 + j*16 + li; w2v[j]=W2[gn]; b1v[j]=b1[gn]; }
  #pragma unroll
  for(int i=0;i<4;i++){
    #pragma unroll
    for(int r=0;r<4;r++){
      float s=0.f;
      #pragma unroll
      for(int j=0;j<4;j++){
        float v = acc[i][j][r] + b1v[j];
        v = v>0.f ? v : 0.f;
        s += v*w2v[j];
      }
      s += __shfl_xor(s,1); s += __shfl_xor(s,2); s += __shfl_xor(s,4); s += __shfl_xor(s,8);
      if(li==0) atomicAdd(&score_pre[m0 + wm*64 + i*16 + q*4 + r], s);
    }
  }
}

// fallback if ws can't hold W1b
__global__ __launch_bounds__(256) void attn_gemm_f32(const short* __restrict__ catT,
    const float* __restrict__ W1, const float* __restrict__ b1, const float* __restrict__ W2,
    float* __restrict__ score_pre){
  const int K = NN;
  int lane = threadIdx.x & 63;
  int wv   = threadIdx.x >> 6;
  int m0 = (blockIdx.x*4 + wv)*64;
  int n0 = blockIdx.y*64;
  int li = lane & 15, q = lane >> 4;
  const short* Ab = catT + (size_t)(m0+li)*K + q*8;
  const float* Bb = W1 + (size_t)(n0+li)*K + q*8;
  f32x4 acc[4][4];
  #pragma unroll
  for(int i=0;i<4;i++)
    #pragma unroll
    for(int j=0;j<4;j++) acc[i][j] = (f32x4){0.f,0.f,0.f,0.f};
  for(int k0=0;k0<K;k0+=32){
    bf16x8 a[4], b[4];
    #pragma unroll
    for(int i=0;i<4;i++) a[i] = *(const bf16x8*)(Ab + (size_t)i*16*K + k0);
    #pragma unroll
    for(int j=0;j<4;j++){
      const float* p = Bb + (size_t)j*16*K + k0;
      float4 f0 = *(const float4*)p;
      float4 f1 = *(const float4*)(p+4);
      bf16x8 t;
      t[0]=f2bf(f0.x); t[1]=f2bf(f0.y); t[2]=f2bf(f0.z); t[3]=f2bf(f0.w);
      t[4]=f2bf(f1.x); t[5]=f2bf(f1.y); t[6]=f2bf(f1.z); t[7]=f2bf(f1.w);
      b[j]=t;
    }
    #pragma unroll
    for(int i=0;i<4;i++)
      #pragma unroll
      for(int j=0;j<4;j++)
        acc[i][j] = __builtin_amdgcn_mfma_f32_16x16x32_bf16(a[i], b[j], acc[i][j], 0, 0, 0);
  }
  float w2v[4], b1v[4];
  #pragma unroll
  for(int j=0;j<4;j++){ int gn=n0+j*16+li; w2v[j]=W2[gn]; b1v[j]=b1[gn]; }
  #pragma unroll
  for(int i=0;i<4;i++){
    #pragma unroll
    for(int r=0;r<4;r++){
      float s=0.f;
      #pragma unroll
      for(int j=0;j<4;j++){
        float v = acc[i][j][r] + b1v[j];
        v = v>0.f ? v : 0.f;
        s += v*w2v[j];
      }
      s += __shfl_xor(s,1); s += __shfl_xor(s,2); s += __shfl_xor(s,4); s += __shfl_xor(s,8);
      if(li==0) atomicAdd(&score_pre[m0 + i*16 + q*4 + r], s);
    }
  }
}

// ---------------- score finalize ----------------
__global__ void k_score(const float* __restrict__ pre, const float* __restrict__ b2,
                        const float* __restrict__ center, const float* __restrict__ clsW,
                        float* __restrict__ sw){
  int d = blockIdx.x*256 + threadIdx.x;
  if(d>=DCATD) return;
  float sc = pre[d] + b2[0];
  sc = 1.f/(1.f+expf(-sc));
  sc -= center[d];
  #pragma unroll
  for(int o=0;o<10;o++) sw[d*10+o] = sc * clsW[(size_t)o*DCATD + d];
}

// ---------------- final ----------------
__global__ __launch_bounds__(64) void k_final(const float* __restrict__ x, const float* __restrict__ o1,
    const float* __restrict__ o2, const float* __restrict__ sw, const float* __restrict__ clsb,
    float* __restrict__ out){
  int i = blockIdx.x, l = threadIdx.x;
  float acc[10];
  #pragma unroll
  for(int o=0;o<10;o++) acc[o]=0.f;
  for(int d=l; d<DCATD; d+=64){
    float v = (d<FD) ? x[(size_t)i*FD + d]
            : (d<FD+HIDD) ? o1[(size_t)i*HIDD + d-FD]
            : o2[(size_t)i*HIDD + d-FD-HIDD];
    const float* s = sw + (size_t)d*10;
    #pragma unroll
    for(int o=0;o<10;o++) acc[o] += v*s[o];
  }
  #pragma unroll
  for(int o=0;o<10;o++){
    float t = acc[o];
    for(int off=32;off;off>>=1) t += __shfl_down(t,off);
    if(l==0) out[(size_t)i*10 + o] = t + clsb[o];
  }
}

extern "C" void kernel_launch(void* const* d_in, const int* in_sizes, int n_in,
                              void* d_out, int out_size, void* d_ws, size_t ws_size,
                              hipStream_t stream) {
  const float* x      = (const float*)d_in[0];
  const int*   ei     = (const int*)d_in[1];
  const float* eattr  = (const float*)d_in[2];
  const float* gn1_w  = (const float*)d_in[3];
  const float* gn1_b  = (const float*)d_in[4];
  const float* gn1_ms = (const float*)d_in[5];
  const float* gn2_w  = (const float*)d_in[6];
  const float* gn2_b  = (const float*)d_in[7];
  const float* gn2_ms = (const float*)d_in[8];
  const float* hg1_W  = (const float*)d_in[9];
  const float* hg1_att= (const float*)d_in[10];
  const float* hg1_b  = (const float*)d_in[11];
  const float* hg2_W  = (const float*)d_in[12];
  const float* hg2_att= (const float*)d_in[13];
  const float* hg2_b  = (const float*)d_in[14];
  const float* fc1_W  = (const float*)d_in[15];
  const float* fc1_b  = (const float*)d_in[16];
  const float* fc2_W  = (const float*)d_in[17];
  const float* fc2_b  = (const float*)d_in[18];
  const float* attn_W1= (const float*)d_in[19];
  const float* attn_b1= (const float*)d_in[20];
  const float* attn_W2= (const float*)d_in[21];
  const float* attn_b2= (const float*)d_in[22];
  const float* cls_W  = (const float*)d_in[23];
  const float* cls_b  = (const float*)d_in[24];
  const float* center = (const float*)d_in[25];
  float* out = (float*)d_out;

  const int* row = ei;
  const int* col = ei + NNZE;

  char* w = (char*)d_ws;
  size_t off = 0;
  auto alloc = [&](size_t bytes)->void*{
    off = (off + 255) & ~(size_t)255;
    void* p = w + off;
    off += bytes;
    return p;
  };
  float* xt    = (float*)alloc((size_t)NN*FD*4);     // used as bf16 (xtb)
  float* ef    = (float*)alloc((size_t)NN*FD*4);     // used as bf16 (efb); later catT
  float* h     = (float*)alloc((size_t)NN*FD*4);
  float* out1  = (float*)alloc((size_t)NN*HIDD*4);
  float* out2  = (float*)alloc((size_t)NN*HIDD*4);
  short* inb   = (short*)alloc((size_t)NN*FD*2);     // normalized bf16 (affdot out)
  short* hbf   = (short*)alloc((size_t)NN*FD*2);     // h bf16 (seg_gather dual out)
  short* wb1   = (short*)alloc((size_t)FD*FD*2);
  short* wb2   = (short*)alloc((size_t)FD*FD*2);
  short* fwb1  = (short*)alloc((size_t)HIDD*FD*2);
  short* fwb2  = (short*)alloc((size_t)HIDD*FD*2);
  int* cnt_col = (int*)alloc(NN*4);                  // adjacent to cnt_row (one memset)
  int* cnt_row = (int*)alloc(NN*4);
  int* col_off = (int*)alloc((NN+1)*4);
  int* row_off = (int*)alloc((NN+1)*4);
  int* col_cur = (int*)alloc(NN*4);
  int* row_cur = (int*)alloc(NN*4);
  int* ceids   = (int*)alloc(NNZE*4);
  int* reids   = (int*)alloc(NNZE*4);
  float* Bn    = (float*)alloc(NN*4);
  float* Dn    = (float*)alloc(NN*4);
  float* a_x   = (float*)alloc(NN*4);
  float* a_e   = (float*)alloc(NN*4);
  float* asm_  = (float*)alloc(NNZE*4);
  float* gsum  = (float*)alloc(FD*4);                // adjacent to gssq (one memset)
  float* gssq  = (float*)alloc(FD*4);
  float* gnA   = (float*)alloc(FD*4);
  float* gnB   = (float*)alloc(FD*4);
  float* wxr   = (float*)alloc(FD*4);
  float* we    = (float*)alloc(FD*4);
  float* score_pre = (float*)alloc(DCATD*4);
  float* sw    = (float*)alloc(DCATD*10*4);
  short* catT  = (short*)ef;   // alias: efb dead by the time catT is built
  short* xtb   = (short*)xt;   // bf16 xt (gemm_lds dual-out)
  short* efb   = (short*)ef;   // bf16 efeat (gather1 out)
  size_t off_before_w1b = off;
  short* W1b   = (short*)alloc((size_t)NN*NN*2);
  bool use_w1b = (off <= ws_size);
  if(!use_w1b) off = off_before_w1b;
  (void)n_in; (void)in_sizes; (void)out_size;

  // ---- CSR build (4 dispatches + 1 memset) ----
  hipMemsetAsync(cnt_col, 0, 2*NN*4, stream);        // covers cnt_col + cnt_row
  k_hist<<<NNZE/256, 256, 0, stream>>>(row, col, cnt_row, cnt_col);
  k_scan2<<<2, 1024, 0, stream>>>(cnt_col, cnt_row, col_off, row_off, col_cur, row_cur, Bn, Dn);
  k_scatter<<<NNZE/256, 256, 0, stream>>>(row, col, col_cur, row_cur, ceids, reids);

  // ---- all weight conversions in one dispatch ----
  int nW1 = use_w1b ? (int)((size_t)NN*NN/2048) : 0;   // 32768 or 0
  k_cvt_all<<<nW1 + 864, 256, 0, stream>>>(nW1, attn_W1, W1b,
      hg1_W, wb1, hg2_W, wb2, fc1_W, fwb1, fc2_W, fwb2);

  for(int layer=0; layer<2; layer++){
    const float* src_feat = (layer==0) ? x : h;
    const float* gW   = (layer==0) ? gn1_w  : gn2_w;
    const float* gB   = (layer==0) ? gn1_b  : gn2_b;
    const float* gMS  = (layer==0) ? gn1_ms : gn2_ms;
    const float* hgW  = (layer==0) ? hg1_W  : hg2_W;
    const float* hgAtt= (layer==0) ? hg1_att: hg2_att;
    const float* hgB  = (layer==0) ? hg1_b  : hg2_b;
    const short* wbL  = (layer==0) ? wb1    : wb2;
    const short* fwbL = (layer==0) ? fwb1   : fwb2;
    const float* fcB  = (layer==0) ? fc1_b  : fc2_b;
    float* fout       = (layer==0) ? out1   : out2;

    hipMemsetAsync(gsum, 0, 2*FD*4, stream);         // covers gsum + gssq
    k_colstats<<<dim3(3,32), 256, 0, stream>>>(src_feat, gsum, gssq);
    k_watt<<<FD, 256, 0, stream>>>(hgW, hgAtt, gsum, gssq, gW, gB, gMS, gnA, gnB, wxr, we);
    k_matvec<<<NN, 64, 0, stream>>>(eattr, we, a_e);
    k_affdot<<<NN, 256, 0, stream>>>(src_feat, gnA, gnB, wxr, inb, a_x);
    // xt produced directly in bf16 (only consumer is gather1)
    gemm_lds<<<dim3(FD/128, NN/128), 256, 0, stream>>>(inb, wbL, nullptr, xtb, NN, FD, FD, nullptr, 1.f);
    k_softmax_seg<<<NN/4, 256, 0, stream>>>(col_off, ceids, row, a_x, a_e, asm_);
    // gather1: bf16 src, bf16-only out (efeat)
    k_seg_gather<<<NN, 192, 0, stream>>>(xtb, col_off, ceids, row, asm_, Bn, nullptr, 1.f, nullptr, efb);
    // gather2: bf16 src, f32 h + bf16 hbf out
    k_seg_gather<<<NN, 192, 0, stream>>>(efb, row_off, reids, col, asm_, Dn, hgB, 0.01f, h, hbf);
    gemm_lds<<<dim3(HIDD/128, NN/128), 256, 0, stream>>>(hbf, fwbL, fout, nullptr, NN, HIDD, FD, fcB, 0.01f);
  }

  // ---- attention over cat = [x, out1, out2] ----
  k_build_catT<<<dim3(NN/32, DCATD/32), dim3(32,8), 0, stream>>>(x, out1, out2, catT);
  hipMemsetAsync(score_pre, 0, DCATD*4, stream);
  if(use_w1b)
    attn_gemm_lds<<<768, 256, 0, stream>>>(catT, W1b, attn_b1, attn_W2, score_pre);
  else
    attn_gemm_f32<<<dim3(DCATD/256, NN/64), 256, 0, stream>>>(catT, attn_W1, attn_b1, attn_W2, score_pre);
  k_score<<<DCATD/256, 256, 0, stream>>>(score_pre, attn_b2, center, cls_W, sw);
  k_final<<<NN, 64, 0, stream>>>(x, out1, out2, sw, cls_b, out);
}

// Round 3
// 1217.666 us; speedup vs baseline: 1.0026x; 1.0026x over previous
//
#include <hip/hip_runtime.h>
#include <cstddef>

#define NN 8192
#define FD 768
#define HIDD 384
#define NNZE 131072
#define DCATD 1536

typedef short bf16x8 __attribute__((ext_vector_type(8)));
typedef float f32x4 __attribute__((ext_vector_type(4)));

__device__ __forceinline__ short f2bf(float f){
  unsigned u = __float_as_uint(f);
  unsigned r = u + 0x7FFFu + ((u>>16)&1u);   // RNE
  return (short)(r>>16);
}
__device__ __forceinline__ float bf2f(short s){
  return __uint_as_float(((unsigned)(unsigned short)s)<<16);
}

// async global -> LDS, 16B per lane. lds ptr wave-uniform; HW scatters lane*16.
__device__ __forceinline__ void async_copy16(void* lds, const void* g){
  __builtin_amdgcn_global_load_lds((__attribute__((address_space(1))) void*)g,
                                   (__attribute__((address_space(3))) void*)lds, 16, 0, 0);
}

// ---------------- CSR build ----------------
__global__ void k_hist(const int* __restrict__ row, const int* __restrict__ col,
                       int* __restrict__ cr, int* __restrict__ cc){
  int e = blockIdx.x*256 + threadIdx.x;
  if(e >= NNZE) return;
  atomicAdd(&cc[col[e]], 1);
  atomicAdd(&cr[row[e]], 1);
}

// 2 blocks: block 0 scans col counts (-> col_off/cur + Bn), block 1 row (-> row_off/cur + Dn)
__global__ __launch_bounds__(1024) void k_scan2(const int* __restrict__ cnt_col,
    const int* __restrict__ cnt_row,
    int* __restrict__ col_off, int* __restrict__ row_off,
    int* __restrict__ col_cur, int* __restrict__ row_cur,
    float* __restrict__ Bn, float* __restrict__ Dn){
  const int* cnt = (blockIdx.x==0) ? cnt_col : cnt_row;
  int* offs = (blockIdx.x==0) ? col_off : row_off;
  int* cur  = (blockIdx.x==0) ? col_cur : row_cur;
  float* rec= (blockIdx.x==0) ? Bn : Dn;
  __shared__ int part[1024];
  int t = threadIdx.x;
  int v[8]; int s = 0;
  #pragma unroll
  for(int j=0;j<8;j++){ v[j]=cnt[t*8+j]; s+=v[j]; }
  part[t]=s; __syncthreads();
  for(int d=1; d<1024; d<<=1){
    int mine = part[t];
    int add = (t>=d)? part[t-d] : 0;
    __syncthreads();
    part[t] = mine + add;
    __syncthreads();
  }
  int excl = part[t]-s;
  #pragma unroll
  for(int j=0;j<8;j++){
    offs[t*8+j]=excl; cur[t*8+j]=excl; excl+=v[j];
    rec[t*8+j] = (v[j]>0) ? 1.f/(float)v[j] : 0.f;
  }
  if(t==1023) offs[8192]=excl;
}

__global__ void k_scatter(const int* __restrict__ row, const int* __restrict__ col,
                          int* __restrict__ ccur, int* __restrict__ rcur,
                          int* __restrict__ ceids, int* __restrict__ reids){
  int e = blockIdx.x*256 + threadIdx.x;
  if(e >= NNZE) return;
  int p = atomicAdd(&ccur[col[e]],1); ceids[p]=e;
  int q = atomicAdd(&rcur[row[e]],1); reids[q]=e;
}

// ---------------- all weight casts in ONE dispatch ----------------
__global__ __launch_bounds__(256) void k_cvt_all(int nW1,
    const float* __restrict__ W1, short* __restrict__ W1b,
    const float* __restrict__ hg1W, short* __restrict__ wb1,
    const float* __restrict__ hg2W, short* __restrict__ wb2,
    const float* __restrict__ fc1W, short* __restrict__ fwb1,
    const float* __restrict__ fc2W, short* __restrict__ fwb2){
  int b = blockIdx.x;
  const float* s; short* d; size_t base;
  if(b < nW1){ s=W1; d=W1b; base=(size_t)b*2048; }
  else {
    int r = b - nW1;
    if(r<288){ s=hg1W; d=wb1; base=(size_t)r*2048; }
    else if(r<576){ s=hg2W; d=wb2; base=(size_t)(r-288)*2048; }
    else if(r<720){ s=fc1W; d=fwb1; base=(size_t)(r-576)*2048; }
    else { s=fc2W; d=fwb2; base=(size_t)(r-720)*2048; }
  }
  size_t i = base + (size_t)threadIdx.x*8;
  float4 f0 = *(const float4*)(s+i);
  float4 f1 = *(const float4*)(s+i+4);
  bf16x8 t;
  t[0]=f2bf(f0.x); t[1]=f2bf(f0.y); t[2]=f2bf(f0.z); t[3]=f2bf(f0.w);
  t[4]=f2bf(f1.x); t[5]=f2bf(f1.y); t[6]=f2bf(f1.z); t[7]=f2bf(f1.w);
  *(bf16x8*)(d+i) = t;
}

// ---------------- GraphNorm stats ----------------
__global__ __launch_bounds__(256) void k_colstats(const float* __restrict__ src,
                                                  float* __restrict__ gs, float* __restrict__ gss){
  int col = blockIdx.x*256 + threadIdx.x;     // 0..767
  int r0 = blockIdx.y*256;
  float s1=0.f, s2=0.f;
  for(int r=0;r<256;r++){
    float v = src[(size_t)(r0+r)*FD + col];
    s1+=v; s2+=v*v;
  }
  atomicAdd(&gs[col], s1);
  atomicAdd(&gss[col], s2);
}

// per-column: W^T·att dots  +  GraphNorm affine coeffs (gn_fin fused)
__global__ __launch_bounds__(256) void k_watt(const float* __restrict__ W, const float* __restrict__ att,
    const float* __restrict__ gs, const float* __restrict__ gss,
    const float* __restrict__ w_, const float* __restrict__ b_, const float* __restrict__ ms_,
    float* __restrict__ gnA, float* __restrict__ gnB,
    float* __restrict__ wxr, float* __restrict__ we){
  int c = blockIdx.x; int t = threadIdx.x;
  float sA=0.f, sB=0.f;
  for(int f=t; f<FD; f+=256){
    float w = W[(size_t)f*FD + c];
    sA += w*att[f];
    sB += w*att[FD+f];
  }
  __shared__ float shA[256], shB[256];
  shA[t]=sA; shB[t]=sB; __syncthreads();
  for(int s=128;s>0;s>>=1){ if(t<s){ shA[t]+=shA[t+s]; shB[t]+=shB[t+s]; } __syncthreads(); }
  if(t==0){
    float mean = gs[c]*(1.f/(float)NN);
    float ex2  = gss[c]*(1.f/(float)NN);
    float ctr  = ms_[c]*mean;
    float var  = ex2 - 2.f*ctr*mean + ctr*ctr;
    float a    = w_[c] / sqrtf(var + 1e-5f);
    gnA[c]=a; gnB[c]=b_[c] - a*ctr;
    wxr[c]=shA[0]; we[c]=shB[0];
  }
}

// a[i] = sum_c src[i,c]*wv[c]   (a_e path)
__global__ __launch_bounds__(64) void k_matvec(const float* __restrict__ src, const float* __restrict__ wv,
    float* __restrict__ out){
  int i = blockIdx.x, l = threadIdx.x;
  float s=0.f;
  for(int c=l;c<FD;c+=64) s += src[(size_t)i*FD+c]*wv[c];
  for(int o=32;o;o>>=1) s += __shfl_down(s,o);
  if(l==0) out[i] = s;
}

// normalized bf16 row + dot with wxr in one pass (affcast + matvec a_x fused)
__global__ __launch_bounds__(256) void k_affdot(const float* __restrict__ src,
    const float* __restrict__ A, const float* __restrict__ B, const float* __restrict__ wxr,
    short* __restrict__ dstb, float* __restrict__ ax){
  int i = blockIdx.x, t = threadIdx.x;
  float p = 0.f;
  #pragma unroll
  for(int k=0;k<3;k++){
    int c = t + k*256;
    float v = A[c]*src[(size_t)i*FD+c] + B[c];
    dstb[(size_t)i*FD+c] = f2bf(v);
    p += v*wxr[c];
  }
  __shared__ float sh[256];
  sh[t]=p; __syncthreads();
  for(int s=128;s>0;s>>=1){ if(t<s) sh[t]+=sh[t+s]; __syncthreads(); }
  if(t==0) ax[i]=sh[0];
}

// ---------------- LDS-staged bf16 NT GEMM: BM=128, BN=64, BK=64 ----------------
// Grid-limited occupancy fix: smaller N-tile doubles block count; LDS 24 KB ->
// 6 blocks/CU (vs 3). 4 waves = 2m x 2n, wave tile 64x32, acc 4x2 (32 VGPR).
__global__ __launch_bounds__(256,6) void gemm_lds(const short* __restrict__ A, const short* __restrict__ B,
    float* __restrict__ C, short* __restrict__ Cb, int M, int N, int K,
    const float* __restrict__ bias, float slope){
  __shared__ __align__(16) short As[2*128*32];   // [kk][128][32]
  __shared__ __align__(16) short Bs[2*64*32];    // [kk][64][32]
  int t = threadIdx.x;
  int w = t>>6, l = t&63;
  int m0 = blockIdx.y*128, n0 = blockIdx.x*64;
  int wm = w>>1, wn = w&1;
  int li = l&15, q = l>>4;
  const short* Ag = A + (size_t)(m0 + w*16 + (l>>2))*K + (l&3)*8;
  const short* Bg = B + (size_t)(n0 + w*16 + (l>>2))*K + (l&3)*8;
  f32x4 acc[4][2];
  #pragma unroll
  for(int i=0;i<4;i++)
    #pragma unroll
    for(int j=0;j<2;j++) acc[i][j] = (f32x4){0.f,0.f,0.f,0.f};
  for(int k0=0;k0<K;k0+=64){
    #pragma unroll
    for(int kk=0;kk<2;kk++){
      async_copy16(&As[kk*4096 + (w*16)*32],        Ag + k0 + kk*32);
      async_copy16(&As[kk*4096 + (64 + w*16)*32],   Ag + (size_t)64*K + k0 + kk*32);
      async_copy16(&Bs[kk*2048 + (w*16)*32],        Bg + k0 + kk*32);
    }
    __syncthreads();
    #pragma unroll
    for(int kk=0;kk<2;kk++){
      bf16x8 a[4], b[2];
      #pragma unroll
      for(int i=0;i<4;i++) a[i] = *(const bf16x8*)&As[kk*4096 + (wm*64 + i*16 + li)*32 + q*8];
      #pragma unroll
      for(int j=0;j<2;j++) b[j] = *(const bf16x8*)&Bs[kk*2048 + (wn*32 + j*16 + li)*32 + q*8];
      #pragma unroll
      for(int i=0;i<4;i++)
        #pragma unroll
        for(int j=0;j<2;j++)
          acc[i][j] = __builtin_amdgcn_mfma_f32_16x16x32_bf16(a[i], b[j], acc[i][j], 0, 0, 0);
    }
    __syncthreads();
  }
  #pragma unroll
  for(int i=0;i<4;i++){
    int gm = m0 + wm*64 + i*16 + q*4;
    #pragma unroll
    for(int j=0;j<2;j++){
      int gn = n0 + wn*32 + j*16 + li;
      float bv = bias ? bias[gn] : 0.f;
      #pragma unroll
      for(int r=0;r<4;r++){
        float vv = acc[i][j][r] + bv;
        vv = (vv>=0.f) ? vv : vv*slope;
        if(C)  C[(size_t)(gm+r)*N + gn] = vv;
        if(Cb) Cb[(size_t)(gm+r)*N + gn] = f2bf(vv);
      }
    }
  }
}

// ---------------- per-segment softmax via CSR ----------------
__global__ __launch_bounds__(256) void k_softmax_seg(const int* __restrict__ offs,
    const int* __restrict__ eids, const int* __restrict__ row,
    const float* __restrict__ ax, const float* __restrict__ ae, float* __restrict__ asm_){
  int seg = blockIdx.x*4 + (threadIdx.x>>6);
  int l = threadIdx.x & 63;
  int beg = offs[seg], end = offs[seg+1];
  if(beg >= end) return;                 // wave-uniform
  float aev = ae[seg];
  float m = -1e30f;
  for(int idx=beg+l; idx<end; idx+=64){
    int e = eids[idx];
    float a = ax[row[e]] + aev; a = (a>=0.f)?a:0.2f*a;
    m = fmaxf(m, a);
  }
  #pragma unroll
  for(int o=1;o<64;o<<=1) m = fmaxf(m, __shfl_xor(m,o));
  float s = 0.f;
  for(int idx=beg+l; idx<end; idx+=64){
    int e = eids[idx];
    float a = ax[row[e]] + aev; a = (a>=0.f)?a:0.2f*a;
    s += expf(a-m);
  }
  #pragma unroll
  for(int o=1;o<64;o<<=1) s += __shfl_xor(s,o);
  float inv = 1.f/(s + 1e-16f);
  for(int idx=beg+l; idx<end; idx+=64){
    int e = eids[idx];
    float a = ax[row[e]] + aev; a = (a>=0.f)?a:0.2f*a;
    asm_[e] = expf(a-m)*inv;
  }
}

// ---------------- segment gather-sum, bf16 source ----------------
__global__ __launch_bounds__(192) void k_seg_gather(const short* __restrict__ srcb,
    const int* __restrict__ offs, const int* __restrict__ eids,
    const int* __restrict__ gidx, const float* __restrict__ alpha_sm,
    const float* __restrict__ segscale, const float* __restrict__ bias, float slope,
    float* __restrict__ dst, short* __restrict__ dstb){
  int c = blockIdx.x, t = threadIdx.x;   // t in [0,192), 4 cols each
  int beg = offs[c], end = offs[c+1];
  float scale = segscale[c];
  __shared__ float wsh[192]; __shared__ int rsh[192];
  float4 acc = {0.f,0.f,0.f,0.f};
  for(int base=beg; base<end; base+=192){
    int idx = base+t;
    if(idx<end){ int e=eids[idx]; wsh[t]=alpha_sm[e]; rsh[t]=gidx[e]; }
    __syncthreads();
    int cnt = min(192, end-base);
    int j=0;
    for(; j+1<cnt; j+=2){
      float w0=wsh[j], w1=wsh[j+1];
      short4 s0 = *((const short4*)(srcb + (size_t)rsh[j]*FD) + t);
      short4 s1 = *((const short4*)(srcb + (size_t)rsh[j+1]*FD) + t);
      acc.x += w0*bf2f(s0.x) + w1*bf2f(s1.x);
      acc.y += w0*bf2f(s0.y) + w1*bf2f(s1.y);
      acc.z += w0*bf2f(s0.z) + w1*bf2f(s1.z);
      acc.w += w0*bf2f(s0.w) + w1*bf2f(s1.w);
    }
    if(j<cnt){
      float w0=wsh[j];
      short4 s0 = *((const short4*)(srcb + (size_t)rsh[j]*FD) + t);
      acc.x += w0*bf2f(s0.x); acc.y += w0*bf2f(s0.y);
      acc.z += w0*bf2f(s0.z); acc.w += w0*bf2f(s0.w);
    }
    __syncthreads();
  }
  acc.x*=scale; acc.y*=scale; acc.z*=scale; acc.w*=scale;
  if(bias){
    float4 bv = *((const float4*)bias + t);
    acc.x+=bv.x; acc.y+=bv.y; acc.z+=bv.z; acc.w+=bv.w;
    acc.x=(acc.x>=0.f)?acc.x:slope*acc.x;
    acc.y=(acc.y>=0.f)?acc.y:slope*acc.y;
    acc.z=(acc.z>=0.f)?acc.z:slope*acc.z;
    acc.w=(acc.w>=0.f)?acc.w:slope*acc.w;
  }
  if(dst) *((float4*)(dst + (size_t)c*FD) + t) = acc;
  if(dstb){
    short4 o; o.x=f2bf(acc.x); o.y=f2bf(acc.y); o.z=f2bf(acc.z); o.w=f2bf(acc.w);
    *((short4*)(dstb + (size_t)c*FD) + t) = o;
  }
}

// ---------------- catT build ----------------
__global__ __launch_bounds__(256) void k_build_catT(const float* __restrict__ x,
    const float* __restrict__ o1, const float* __restrict__ o2, short* __restrict__ catT){
  __shared__ float tile[32][33];
  int i0 = blockIdx.x*32, d0 = blockIdx.y*32;
  int tx = threadIdx.x, ty = threadIdx.y;   // 32 x 8
  const float* src; int dof, ld;
  if(d0 < FD){ src=x; dof=d0; ld=FD; }
  else if(d0 < FD+HIDD){ src=o1; dof=d0-FD; ld=HIDD; }
  else { src=o2; dof=d0-FD-HIDD; ld=HIDD; }
  for(int yy=ty; yy<32; yy+=8)
    tile[yy][tx] = src[(size_t)(i0+yy)*ld + dof + tx];
  __syncthreads();
  for(int yy=ty; yy<32; yy+=8)
    catT[(size_t)(d0+yy)*NN + i0 + tx] = f2bf(tile[tx][yy]);
}

// ---------------- attention mega-GEMM: BM=128, BN=64, BK=64, 1536 blocks ------------
// Same 2-phase structure; grid 768->1536 blocks (3->6 blocks/CU) to hide the
// per-iter vmcnt(0) drain (loads resolve from L3/HBM since W1b > L2).
// XCD swizzle: blocks on XCD cc get contiguous n-chunk [cc*16, cc*16+16) -> B panel
// shared within one XCD's L2.
__global__ __launch_bounds__(256,6) void attn_gemm_lds(const short* __restrict__ catT,
    const short* __restrict__ W1b, const float* __restrict__ b1, const float* __restrict__ W2,
    float* __restrict__ score_pre){
  const int K = NN;
  __shared__ __align__(16) short As[2*128*32];
  __shared__ __align__(16) short Bs[2*64*32];
  int id = blockIdx.x;             // 0..1535
  int cc = id&7, g = id>>3;        // g 0..191
  int m_idx = g>>4;                // 0..11
  int n_idx = cc*16 + (g&15);      // 0..127
  int m0 = m_idx*128, n0 = n_idx*64;
  int t = threadIdx.x;
  int w = t>>6, l = t&63;
  int wm = w>>1, wn = w&1;
  int li = l&15, q = l>>4;
  const short* Ag = catT + (size_t)(m0 + w*16 + (l>>2))*K + (l&3)*8;
  const short* Bg = W1b + (size_t)(n0 + w*16 + (l>>2))*K + (l&3)*8;
  f32x4 acc[4][2];
  #pragma unroll
  for(int i=0;i<4;i++)
    #pragma unroll
    for(int j=0;j<2;j++) acc[i][j] = (f32x4){0.f,0.f,0.f,0.f};
  for(int k0=0;k0<K;k0+=64){
    #pragma unroll
    for(int kk=0;kk<2;kk++){
      async_copy16(&As[kk*4096 + (w*16)*32],        Ag + k0 + kk*32);
      async_copy16(&As[kk*4096 + (64 + w*16)*32],   Ag + (size_t)64*K + k0 + kk*32);
      async_copy16(&Bs[kk*2048 + (w*16)*32],        Bg + k0 + kk*32);
    }
    __syncthreads();
    #pragma unroll
    for(int kk=0;kk<2;kk++){
      bf16x8 a[4], b[2];
      #pragma unroll
      for(int i=0;i<4;i++) a[i] = *(const bf16x8*)&As[kk*4096 + (wm*64 + i*16 + li)*32 + q*8];
      #pragma unroll
      for(int j=0;j<2;j++) b[j] = *(const bf16x8*)&Bs[kk*2048 + (wn*32 + j*16 + li)*32 + q*8];
      #pragma unroll
      for(int i=0;i<4;i++)
        #pragma unroll
        for(int j=0;j<2;j++)
          acc[i][j] = __builtin_amdgcn_mfma_f32_16x16x32_bf16(a[i], b[j], acc[i][j], 0, 0, 0);
    }
    __syncthreads();
  }
  float w2v[2], b1v[2];
  #pragma unroll
  for(int j=0;j<2;j++){ int gn = n0 + wn*32 + j*16 + li; w2v[j]=W2[gn]; b1v[j]=b1[gn]; }
  #pragma unroll
  for(int i=0;i<4;i++){
    #pragma unroll
    for(int r=0;r<4;r++){
      float s=0.f;
      #pragma unroll
      for(int j=0;j<2;j++){
        float v = acc[i][j][r] + b1v[j];
        v = v>0.f ? v : 0.f;
        s += v*w2v[j];
      }
      s += __shfl_xor(s,1); s += __shfl_xor(s,2); s += __shfl_xor(s,4); s += __shfl_xor(s,8);
      if(li==0) atomicAdd(&score_pre[m0 + wm*64 + i*16 + q*4 + r], s);
    }
  }
}

// fallback if ws can't hold W1b
__global__ __launch_bounds__(256) void attn_gemm_f32(const short* __restrict__ catT,
    const float* __restrict__ W1, const float* __restrict__ b1, const float* __restrict__ W2,
    float* __restrict__ score_pre){
  const int K = NN;
  int lane = threadIdx.x & 63;
  int wv   = threadIdx.x >> 6;
  int m0 = (blockIdx.x*4 + wv)*64;
  int n0 = blockIdx.y*64;
  int li = lane & 15, q = lane >> 4;
  const short* Ab = catT + (size_t)(m0+li)*K + q*8;
  const float* Bb = W1 + (size_t)(n0+li)*K + q*8;
  f32x4 acc[4][4];
  #pragma unroll
  for(int i=0;i<4;i++)
    #pragma unroll
    for(int j=0;j<4;j++) acc[i][j] = (f32x4){0.f,0.f,0.f,0.f};
  for(int k0=0;k0<K;k0+=32){
    bf16x8 a[4], b[4];
    #pragma unroll
    for(int i=0;i<4;i++) a[i] = *(const bf16x8*)(Ab + (size_t)i*16*K + k0);
    #pragma unroll
    for(int j=0;j<4;j++){
      const float* p = Bb + (size_t)j*16*K + k0;
      float4 f0 = *(const float4*)p;
      float4 f1 = *(const float4*)(p+4);
      bf16x8 t;
      t[0]=f2bf(f0.x); t[1]=f2bf(f0.y); t[2]=f2bf(f0.z); t[3]=f2bf(f0.w);
      t[4]=f2bf(f1.x); t[5]=f2bf(f1.y); t[6]=f2bf(f1.z); t[7]=f2bf(f1.w);
      b[j]=t;
    }
    #pragma unroll
    for(int i=0;i<4;i++)
      #pragma unroll
      for(int j=0;j<4;j++)
        acc[i][j] = __builtin_amdgcn_mfma_f32_16x16x32_bf16(a[i], b[j], acc[i][j], 0, 0, 0);
  }
  float w2v[4], b1v[4];
  #pragma unroll
  for(int j=0;j<4;j++){ int gn=n0+j*16+li; w2v[j]=W2[gn]; b1v[j]=b1[gn]; }
  #pragma unroll
  for(int i=0;i<4;i++){
    #pragma unroll
    for(int r=0;r<4;r++){
      float s=0.f;
      #pragma unroll
      for(int j=0;j<4;j++){
        float v = acc[i][j][r] + b1v[j];
        v = v>0.f ? v : 0.f;
        s += v*w2v[j];
      }
      s += __shfl_xor(s,1); s += __shfl_xor(s,2); s += __shfl_xor(s,4); s += __shfl_xor(s,8);
      if(li==0) atomicAdd(&score_pre[m0 + i*16 + q*4 + r], s);
    }
  }
}

// ---------------- score finalize ----------------
__global__ void k_score(const float* __restrict__ pre, const float* __restrict__ b2,
                        const float* __restrict__ center, const float* __restrict__ clsW,
                        float* __restrict__ sw){
  int d = blockIdx.x*256 + threadIdx.x;
  if(d>=DCATD) return;
  float sc = pre[d] + b2[0];
  sc = 1.f/(1.f+expf(-sc));
  sc -= center[d];
  #pragma unroll
  for(int o=0;o<10;o++) sw[d*10+o] = sc * clsW[(size_t)o*DCATD + d];
}

// ---------------- final ----------------
__global__ __launch_bounds__(64) void k_final(const float* __restrict__ x, const float* __restrict__ o1,
    const float* __restrict__ o2, const float* __restrict__ sw, const float* __restrict__ clsb,
    float* __restrict__ out){
  int i = blockIdx.x, l = threadIdx.x;
  float acc[10];
  #pragma unroll
  for(int o=0;o<10;o++) acc[o]=0.f;
  for(int d=l; d<DCATD; d+=64){
    float v = (d<FD) ? x[(size_t)i*FD + d]
            : (d<FD+HIDD) ? o1[(size_t)i*HIDD + d-FD]
            : o2[(size_t)i*HIDD + d-FD-HIDD];
    const float* s = sw + (size_t)d*10;
    #pragma unroll
    for(int o=0;o<10;o++) acc[o] += v*s[o];
  }
  #pragma unroll
  for(int o=0;o<10;o++){
    float t = acc[o];
    for(int off=32;off;off>>=1) t += __shfl_down(t,off);
    if(l==0) out[(size_t)i*10 + o] = t + clsb[o];
  }
}

extern "C" void kernel_launch(void* const* d_in, const int* in_sizes, int n_in,
                              void* d_out, int out_size, void* d_ws, size_t ws_size,
                              hipStream_t stream) {
  const float* x      = (const float*)d_in[0];
  const int*   ei     = (const int*)d_in[1];
  const float* eattr  = (const float*)d_in[2];
  const float* gn1_w  = (const float*)d_in[3];
  const float* gn1_b  = (const float*)d_in[4];
  const float* gn1_ms = (const float*)d_in[5];
  const float* gn2_w  = (const float*)d_in[6];
  const float* gn2_b  = (const float*)d_in[7];
  const float* gn2_ms = (const float*)d_in[8];
  const float* hg1_W  = (const float*)d_in[9];
  const float* hg1_att= (const float*)d_in[10];
  const float* hg1_b  = (const float*)d_in[11];
  const float* hg2_W  = (const float*)d_in[12];
  const float* hg2_att= (const float*)d_in[13];
  const float* hg2_b  = (const float*)d_in[14];
  const float* fc1_W  = (const float*)d_in[15];
  const float* fc1_b  = (const float*)d_in[16];
  const float* fc2_W  = (const float*)d_in[17];
  const float* fc2_b  = (const float*)d_in[18];
  const float* attn_W1= (const float*)d_in[19];
  const float* attn_b1= (const float*)d_in[20];
  const float* attn_W2= (const float*)d_in[21];
  const float* attn_b2= (const float*)d_in[22];
  const float* cls_W  = (const float*)d_in[23];
  const float* cls_b  = (const float*)d_in[24];
  const float* center = (const float*)d_in[25];
  float* out = (float*)d_out;

  const int* row = ei;
  const int* col = ei + NNZE;

  char* w = (char*)d_ws;
  size_t off = 0;
  auto alloc = [&](size_t bytes)->void*{
    off = (off + 255) & ~(size_t)255;
    void* p = w + off;
    off += bytes;
    return p;
  };
  float* xt    = (float*)alloc((size_t)NN*FD*4);     // used as bf16 (xtb)
  float* ef    = (float*)alloc((size_t)NN*FD*4);     // used as bf16 (efb); later catT
  float* h     = (float*)alloc((size_t)NN*FD*4);
  float* out1  = (float*)alloc((size_t)NN*HIDD*4);
  float* out2  = (float*)alloc((size_t)NN*HIDD*4);
  short* inb   = (short*)alloc((size_t)NN*FD*2);     // normalized bf16 (affdot out)
  short* hbf   = (short*)alloc((size_t)NN*FD*2);     // h bf16 (seg_gather dual out)
  short* wb1   = (short*)alloc((size_t)FD*FD*2);
  short* wb2   = (short*)alloc((size_t)FD*FD*2);
  short* fwb1  = (short*)alloc((size_t)HIDD*FD*2);
  short* fwb2  = (short*)alloc((size_t)HIDD*FD*2);
  int* cnt_col = (int*)alloc(NN*4);                  // adjacent to cnt_row (one memset)
  int* cnt_row = (int*)alloc(NN*4);
  int* col_off = (int*)alloc((NN+1)*4);
  int* row_off = (int*)alloc((NN+1)*4);
  int* col_cur = (int*)alloc(NN*4);
  int* row_cur = (int*)alloc(NN*4);
  int* ceids   = (int*)alloc(NNZE*4);
  int* reids   = (int*)alloc(NNZE*4);
  float* Bn    = (float*)alloc(NN*4);
  float* Dn    = (float*)alloc(NN*4);
  float* a_x   = (float*)alloc(NN*4);
  float* a_e   = (float*)alloc(NN*4);
  float* asm_  = (float*)alloc(NNZE*4);
  float* gsum  = (float*)alloc(FD*4);                // adjacent to gssq (one memset)
  float* gssq  = (float*)alloc(FD*4);
  float* gnA   = (float*)alloc(FD*4);
  float* gnB   = (float*)alloc(FD*4);
  float* wxr   = (float*)alloc(FD*4);
  float* we    = (float*)alloc(FD*4);
  float* score_pre = (float*)alloc(DCATD*4);
  float* sw    = (float*)alloc(DCATD*10*4);
  short* catT  = (short*)ef;   // alias: efb dead by the time catT is built
  short* xtb   = (short*)xt;   // bf16 xt (gemm_lds dual-out)
  short* efb   = (short*)ef;   // bf16 efeat (gather1 out)
  size_t off_before_w1b = off;
  short* W1b   = (short*)alloc((size_t)NN*NN*2);
  bool use_w1b = (off <= ws_size);
  if(!use_w1b) off = off_before_w1b;
  (void)n_in; (void)in_sizes; (void)out_size;

  // ---- CSR build (4 dispatches + 1 memset) ----
  hipMemsetAsync(cnt_col, 0, 2*NN*4, stream);        // covers cnt_col + cnt_row
  k_hist<<<NNZE/256, 256, 0, stream>>>(row, col, cnt_row, cnt_col);
  k_scan2<<<2, 1024, 0, stream>>>(cnt_col, cnt_row, col_off, row_off, col_cur, row_cur, Bn, Dn);
  k_scatter<<<NNZE/256, 256, 0, stream>>>(row, col, col_cur, row_cur, ceids, reids);

  // ---- all weight conversions in one dispatch ----
  int nW1 = use_w1b ? (int)((size_t)NN*NN/2048) : 0;   // 32768 or 0
  k_cvt_all<<<nW1 + 864, 256, 0, stream>>>(nW1, attn_W1, W1b,
      hg1_W, wb1, hg2_W, wb2, fc1_W, fwb1, fc2_W, fwb2);

  for(int layer=0; layer<2; layer++){
    const float* src_feat = (layer==0) ? x : h;
    const float* gW   = (layer==0) ? gn1_w  : gn2_w;
    const float* gB   = (layer==0) ? gn1_b  : gn2_b;
    const float* gMS  = (layer==0) ? gn1_ms : gn2_ms;
    const float* hgW  = (layer==0) ? hg1_W  : hg2_W;
    const float* hgAtt= (layer==0) ? hg1_att: hg2_att;
    const float* hgB  = (layer==0) ? hg1_b  : hg2_b;
    const short* wbL  = (layer==0) ? wb1    : wb2;
    const short* fwbL = (layer==0) ? fwb1   : fwb2;
    const float* fcB  = (layer==0) ? fc1_b  : fc2_b;
    float* fout       = (layer==0) ? out1   : out2;

    hipMemsetAsync(gsum, 0, 2*FD*4, stream);         // covers gsum + gssq
    k_colstats<<<dim3(3,32), 256, 0, stream>>>(src_feat, gsum, gssq);
    k_watt<<<FD, 256, 0, stream>>>(hgW, hgAtt, gsum, gssq, gW, gB, gMS, gnA, gnB, wxr, we);
    k_matvec<<<NN, 64, 0, stream>>>(eattr, we, a_e);
    k_affdot<<<NN, 256, 0, stream>>>(src_feat, gnA, gnB, wxr, inb, a_x);
    // xt produced directly in bf16 (only consumer is gather1)
    gemm_lds<<<dim3(FD/64, NN/128), 256, 0, stream>>>(inb, wbL, nullptr, xtb, NN, FD, FD, nullptr, 1.f);
    k_softmax_seg<<<NN/4, 256, 0, stream>>>(col_off, ceids, row, a_x, a_e, asm_);
    // gather1: bf16 src, bf16-only out (efeat)
    k_seg_gather<<<NN, 192, 0, stream>>>(xtb, col_off, ceids, row, asm_, Bn, nullptr, 1.f, nullptr, efb);
    // gather2: bf16 src, f32 h + bf16 hbf out
    k_seg_gather<<<NN, 192, 0, stream>>>(efb, row_off, reids, col, asm_, Dn, hgB, 0.01f, h, hbf);
    gemm_lds<<<dim3(HIDD/64, NN/128), 256, 0, stream>>>(hbf, fwbL, fout, nullptr, NN, HIDD, FD, fcB, 0.01f);
  }

  // ---- attention over cat = [x, out1, out2] ----
  k_build_catT<<<dim3(NN/32, DCATD/32), dim3(32,8), 0, stream>>>(x, out1, out2, catT);
  hipMemsetAsync(score_pre, 0, DCATD*4, stream);
  if(use_w1b)
    attn_gemm_lds<<<1536, 256, 0, stream>>>(catT, W1b, attn_b1, attn_W2, score_pre);
  else
    attn_gemm_f32<<<dim3(DCATD/256, NN/64), 256, 0, stream>>>(catT, attn_W1, attn_b1, attn_W2, score_pre);
  k_score<<<DCATD/256, 256, 0, stream>>>(score_pre, attn_b2, center, cls_W, sw);
  k_final<<<NN, 64, 0, stream>>>(x, out1, out2, sw, cls_b, out);
}

// Round 5
// 1086.843 us; speedup vs baseline: 1.1233x; 1.1204x over previous
//
#include <hip/hip_runtime.h>
#include <cstddef>

#define NN 8192
#define FD 768
#define HIDD 384
#define NNZE 131072
#define DCATD 1536

typedef short bf16x8 __attribute__((ext_vector_type(8)));
typedef float f32x4 __attribute__((ext_vector_type(4)));

__device__ __forceinline__ short f2bf(float f){
  unsigned u = __float_as_uint(f);
  unsigned r = u + 0x7FFFu + ((u>>16)&1u);   // RNE
  return (short)(r>>16);
}
__device__ __forceinline__ float bf2f(short s){
  return __uint_as_float(((unsigned)(unsigned short)s)<<16);
}

// async global -> LDS, 16B per lane. lds ptr wave-uniform; HW scatters lane*16.
__device__ __forceinline__ void async_copy16(void* lds, const void* g){
  __builtin_amdgcn_global_load_lds((__attribute__((address_space(1))) void*)g,
                                   (__attribute__((address_space(3))) void*)lds, 16, 0, 0);
}

#define SB0() __builtin_amdgcn_sched_barrier(0)

// ---------------- CSR build ----------------
__global__ void k_hist(const int* __restrict__ row, const int* __restrict__ col,
                       int* __restrict__ cr, int* __restrict__ cc){
  int e = blockIdx.x*256 + threadIdx.x;
  if(e >= NNZE) return;
  atomicAdd(&cc[col[e]], 1);
  atomicAdd(&cr[row[e]], 1);
}

__global__ __launch_bounds__(1024) void k_scan2(const int* __restrict__ cnt_col,
    const int* __restrict__ cnt_row,
    int* __restrict__ col_off, int* __restrict__ row_off,
    int* __restrict__ col_cur, int* __restrict__ row_cur,
    float* __restrict__ Bn, float* __restrict__ Dn){
  const int* cnt = (blockIdx.x==0) ? cnt_col : cnt_row;
  int* offs = (blockIdx.x==0) ? col_off : row_off;
  int* cur  = (blockIdx.x==0) ? col_cur : row_cur;
  float* rec= (blockIdx.x==0) ? Bn : Dn;
  __shared__ int part[1024];
  int t = threadIdx.x;
  int v[8]; int s = 0;
  #pragma unroll
  for(int j=0;j<8;j++){ v[j]=cnt[t*8+j]; s+=v[j]; }
  part[t]=s; __syncthreads();
  for(int d=1; d<1024; d<<=1){
    int mine = part[t];
    int add = (t>=d)? part[t-d] : 0;
    __syncthreads();
    part[t] = mine + add;
    __syncthreads();
  }
  int excl = part[t]-s;
  #pragma unroll
  for(int j=0;j<8;j++){
    offs[t*8+j]=excl; cur[t*8+j]=excl; excl+=v[j];
    rec[t*8+j] = (v[j]>0) ? 1.f/(float)v[j] : 0.f;
  }
  if(t==1023) offs[8192]=excl;
}

__global__ void k_scatter(const int* __restrict__ row, const int* __restrict__ col,
                          int* __restrict__ ccur, int* __restrict__ rcur,
                          int* __restrict__ ceids, int* __restrict__ reids){
  int e = blockIdx.x*256 + threadIdx.x;
  if(e >= NNZE) return;
  int p = atomicAdd(&ccur[col[e]],1); ceids[p]=e;
  int q = atomicAdd(&rcur[row[e]],1); reids[q]=e;
}

// ---------------- all weight casts in ONE dispatch ----------------
__global__ __launch_bounds__(256) void k_cvt_all(int nW1,
    const float* __restrict__ W1, short* __restrict__ W1b,
    const float* __restrict__ hg1W, short* __restrict__ wb1,
    const float* __restrict__ hg2W, short* __restrict__ wb2,
    const float* __restrict__ fc1W, short* __restrict__ fwb1,
    const float* __restrict__ fc2W, short* __restrict__ fwb2){
  int b = blockIdx.x;
  const float* s; short* d; size_t base;
  if(b < nW1){ s=W1; d=W1b; base=(size_t)b*2048; }
  else {
    int r = b - nW1;
    if(r<288){ s=hg1W; d=wb1; base=(size_t)r*2048; }
    else if(r<576){ s=hg2W; d=wb2; base=(size_t)(r-288)*2048; }
    else if(r<720){ s=fc1W; d=fwb1; base=(size_t)(r-576)*2048; }
    else { s=fc2W; d=fwb2; base=(size_t)(r-720)*2048; }
  }
  size_t i = base + (size_t)threadIdx.x*8;
  float4 f0 = *(const float4*)(s+i);
  float4 f1 = *(const float4*)(s+i+4);
  bf16x8 t;
  t[0]=f2bf(f0.x); t[1]=f2bf(f0.y); t[2]=f2bf(f0.z); t[3]=f2bf(f0.w);
  t[4]=f2bf(f1.x); t[5]=f2bf(f1.y); t[6]=f2bf(f1.z); t[7]=f2bf(f1.w);
  *(bf16x8*)(d+i) = t;
}

// ---------------- GraphNorm stats ----------------
__global__ __launch_bounds__(256) void k_colstats(const float* __restrict__ src,
                                                  float* __restrict__ gs, float* __restrict__ gss){
  int col = blockIdx.x*256 + threadIdx.x;     // 0..767
  int r0 = blockIdx.y*256;
  float s1=0.f, s2=0.f;
  for(int r=0;r<256;r++){
    float v = src[(size_t)(r0+r)*FD + col];
    s1+=v; s2+=v*v;
  }
  atomicAdd(&gs[col], s1);
  atomicAdd(&gss[col], s2);
}

// per-column: W^T·att dots  +  GraphNorm affine coeffs (gn_fin fused)
__global__ __launch_bounds__(256) void k_watt(const float* __restrict__ W, const float* __restrict__ att,
    const float* __restrict__ gs, const float* __restrict__ gss,
    const float* __restrict__ w_, const float* __restrict__ b_, const float* __restrict__ ms_,
    float* __restrict__ gnA, float* __restrict__ gnB,
    float* __restrict__ wxr, float* __restrict__ we){
  int c = blockIdx.x; int t = threadIdx.x;
  float sA=0.f, sB=0.f;
  for(int f=t; f<FD; f+=256){
    float w = W[(size_t)f*FD + c];
    sA += w*att[f];
    sB += w*att[FD+f];
  }
  __shared__ float shA[256], shB[256];
  shA[t]=sA; shB[t]=sB; __syncthreads();
  for(int s=128;s>0;s>>=1){ if(t<s){ shA[t]+=shA[t+s]; shB[t]+=shB[t+s]; } __syncthreads(); }
  if(t==0){
    float mean = gs[c]*(1.f/(float)NN);
    float ex2  = gss[c]*(1.f/(float)NN);
    float ctr  = ms_[c]*mean;
    float var  = ex2 - 2.f*ctr*mean + ctr*ctr;
    float a    = w_[c] / sqrtf(var + 1e-5f);
    gnA[c]=a; gnB[c]=b_[c] - a*ctr;
    wxr[c]=shA[0]; we[c]=shB[0];
  }
}

// a[i] = sum_c src[i,c]*wv[c]   (a_e path)
__global__ __launch_bounds__(64) void k_matvec(const float* __restrict__ src, const float* __restrict__ wv,
    float* __restrict__ out){
  int i = blockIdx.x, l = threadIdx.x;
  float s=0.f;
  for(int c=l;c<FD;c+=64) s += src[(size_t)i*FD+c]*wv[c];
  for(int o=32;o;o>>=1) s += __shfl_down(s,o);
  if(l==0) out[i] = s;
}

// normalized bf16 row + dot with wxr in one pass (affcast + matvec a_x fused)
__global__ __launch_bounds__(256) void k_affdot(const float* __restrict__ src,
    const float* __restrict__ A, const float* __restrict__ B, const float* __restrict__ wxr,
    short* __restrict__ dstb, float* __restrict__ ax){
  int i = blockIdx.x, t = threadIdx.x;
  float p = 0.f;
  #pragma unroll
  for(int k=0;k<3;k++){
    int c = t + k*256;
    float v = A[c]*src[(size_t)i*FD+c] + B[c];
    dstb[(size_t)i*FD+c] = f2bf(v);
    p += v*wxr[c];
  }
  __shared__ float sh[256];
  sh[t]=p; __syncthreads();
  for(int s=128;s>0;s>>=1){ if(t<s) sh[t]+=sh[t+s]; __syncthreads(); }
  if(t==0) ax[i]=sh[0];
}

// ---------------- LDS-staged bf16 NT GEMM: BM=128, BN=64, BK=64 (layer GEMMs) -------
__global__ __launch_bounds__(256,6) void gemm_lds(const short* __restrict__ A, const short* __restrict__ B,
    float* __restrict__ C, short* __restrict__ Cb, int M, int N, int K,
    const float* __restrict__ bias, float slope){
  __shared__ __align__(16) short As[2*128*32];   // [kk][128][32]
  __shared__ __align__(16) short Bs[2*64*32];    // [kk][64][32]
  int t = threadIdx.x;
  int w = t>>6, l = t&63;
  int m0 = blockIdx.y*128, n0 = blockIdx.x*64;
  int wm = w>>1, wn = w&1;
  int li = l&15, q = l>>4;
  const short* Ag = A + (size_t)(m0 + w*16 + (l>>2))*K + (l&3)*8;
  const short* Bg = B + (size_t)(n0 + w*16 + (l>>2))*K + (l&3)*8;
  f32x4 acc[4][2];
  #pragma unroll
  for(int i=0;i<4;i++)
    #pragma unroll
    for(int j=0;j<2;j++) acc[i][j] = (f32x4){0.f,0.f,0.f,0.f};
  for(int k0=0;k0<K;k0+=64){
    #pragma unroll
    for(int kk=0;kk<2;kk++){
      async_copy16(&As[kk*4096 + (w*16)*32],        Ag + k0 + kk*32);
      async_copy16(&As[kk*4096 + (64 + w*16)*32],   Ag + (size_t)64*K + k0 + kk*32);
      async_copy16(&Bs[kk*2048 + (w*16)*32],        Bg + k0 + kk*32);
    }
    __syncthreads();
    #pragma unroll
    for(int kk=0;kk<2;kk++){
      bf16x8 a[4], b[2];
      #pragma unroll
      for(int i=0;i<4;i++) a[i] = *(const bf16x8*)&As[kk*4096 + (wm*64 + i*16 + li)*32 + q*8];
      #pragma unroll
      for(int j=0;j<2;j++) b[j] = *(const bf16x8*)&Bs[kk*2048 + (wn*32 + j*16 + li)*32 + q*8];
      #pragma unroll
      for(int i=0;i<4;i++)
        #pragma unroll
        for(int j=0;j<2;j++)
          acc[i][j] = __builtin_amdgcn_mfma_f32_16x16x32_bf16(a[i], b[j], acc[i][j], 0, 0, 0);
    }
    __syncthreads();
  }
  #pragma unroll
  for(int i=0;i<4;i++){
    int gm = m0 + wm*64 + i*16 + q*4;
    #pragma unroll
    for(int j=0;j<2;j++){
      int gn = n0 + wn*32 + j*16 + li;
      float bv = bias ? bias[gn] : 0.f;
      #pragma unroll
      for(int r=0;r<4;r++){
        float vv = acc[i][j][r] + bv;
        vv = (vv>=0.f) ? vv : vv*slope;
        if(C)  C[(size_t)(gm+r)*N + gn] = vv;
        if(Cb) Cb[(size_t)(gm+r)*N + gn] = f2bf(vv);
      }
    }
  }
}

// ---------------- per-segment softmax via CSR ----------------
__global__ __launch_bounds__(256) void k_softmax_seg(const int* __restrict__ offs,
    const int* __restrict__ eids, const int* __restrict__ row,
    const float* __restrict__ ax, const float* __restrict__ ae, float* __restrict__ asm_){
  int seg = blockIdx.x*4 + (threadIdx.x>>6);
  int l = threadIdx.x & 63;
  int beg = offs[seg], end = offs[seg+1];
  if(beg >= end) return;                 // wave-uniform
  float aev = ae[seg];
  float m = -1e30f;
  for(int idx=beg+l; idx<end; idx+=64){
    int e = eids[idx];
    float a = ax[row[e]] + aev; a = (a>=0.f)?a:0.2f*a;
    m = fmaxf(m, a);
  }
  #pragma unroll
  for(int o=1;o<64;o<<=1) m = fmaxf(m, __shfl_xor(m,o));
  float s = 0.f;
  for(int idx=beg+l; idx<end; idx+=64){
    int e = eids[idx];
    float a = ax[row[e]] + aev; a = (a>=0.f)?a:0.2f*a;
    s += expf(a-m);
  }
  #pragma unroll
  for(int o=1;o<64;o<<=1) s += __shfl_xor(s,o);
  float inv = 1.f/(s + 1e-16f);
  for(int idx=beg+l; idx<end; idx+=64){
    int e = eids[idx];
    float a = ax[row[e]] + aev; a = (a>=0.f)?a:0.2f*a;
    asm_[e] = expf(a-m)*inv;
  }
}

// ---------------- segment gather-sum, bf16 source ----------------
__global__ __launch_bounds__(192) void k_seg_gather(const short* __restrict__ srcb,
    const int* __restrict__ offs, const int* __restrict__ eids,
    const int* __restrict__ gidx, const float* __restrict__ alpha_sm,
    const float* __restrict__ segscale, const float* __restrict__ bias, float slope,
    float* __restrict__ dst, short* __restrict__ dstb){
  int c = blockIdx.x, t = threadIdx.x;   // t in [0,192), 4 cols each
  int beg = offs[c], end = offs[c+1];
  float scale = segscale[c];
  __shared__ float wsh[192]; __shared__ int rsh[192];
  float4 acc = {0.f,0.f,0.f,0.f};
  for(int base=beg; base<end; base+=192){
    int idx = base+t;
    if(idx<end){ int e=eids[idx]; wsh[t]=alpha_sm[e]; rsh[t]=gidx[e]; }
    __syncthreads();
    int cnt = min(192, end-base);
    int j=0;
    for(; j+1<cnt; j+=2){
      float w0=wsh[j], w1=wsh[j+1];
      short4 s0 = *((const short4*)(srcb + (size_t)rsh[j]*FD) + t);
      short4 s1 = *((const short4*)(srcb + (size_t)rsh[j+1]*FD) + t);
      acc.x += w0*bf2f(s0.x) + w1*bf2f(s1.x);
      acc.y += w0*bf2f(s0.y) + w1*bf2f(s1.y);
      acc.z += w0*bf2f(s0.z) + w1*bf2f(s1.z);
      acc.w += w0*bf2f(s0.w) + w1*bf2f(s1.w);
    }
    if(j<cnt){
      float w0=wsh[j];
      short4 s0 = *((const short4*)(srcb + (size_t)rsh[j]*FD) + t);
      acc.x += w0*bf2f(s0.x); acc.y += w0*bf2f(s0.y);
      acc.z += w0*bf2f(s0.z); acc.w += w0*bf2f(s0.w);
    }
    __syncthreads();
  }
  acc.x*=scale; acc.y*=scale; acc.z*=scale; acc.w*=scale;
  if(bias){
    float4 bv = *((const float4*)bias + t);
    acc.x+=bv.x; acc.y+=bv.y; acc.z+=bv.z; acc.w+=bv.w;
    acc.x=(acc.x>=0.f)?acc.x:slope*acc.x;
    acc.y=(acc.y>=0.f)?acc.y:slope*acc.y;
    acc.z=(acc.z>=0.f)?acc.z:slope*acc.z;
    acc.w=(acc.w>=0.f)?acc.w:slope*acc.w;
  }
  if(dst) *((float4*)(dst + (size_t)c*FD) + t) = acc;
  if(dstb){
    short4 o; o.x=f2bf(acc.x); o.y=f2bf(acc.y); o.z=f2bf(acc.z); o.w=f2bf(acc.w);
    *((short4*)(dstb + (size_t)c*FD) + t) = o;
  }
}

// ---------------- catT build ----------------
__global__ __launch_bounds__(256) void k_build_catT(const float* __restrict__ x,
    const float* __restrict__ o1, const float* __restrict__ o2, short* __restrict__ catT){
  __shared__ float tile[32][33];
  int i0 = blockIdx.x*32, d0 = blockIdx.y*32;
  int tx = threadIdx.x, ty = threadIdx.y;   // 32 x 8
  const float* src; int dof, ld;
  if(d0 < FD){ src=x; dof=d0; ld=FD; }
  else if(d0 < FD+HIDD){ src=o1; dof=d0-FD; ld=HIDD; }
  else { src=o2; dof=d0-FD-HIDD; ld=HIDD; }
  for(int yy=ty; yy<32; yy+=8)
    tile[yy][tx] = src[(size_t)(i0+yy)*ld + dof + tx];
  __syncthreads();
  for(int yy=ty; yy<32; yy+=8)
    catT[(size_t)(d0+yy)*NN + i0 + tx] = f2bf(tile[tx][yy]);
}

// ================== 8-phase 256x256 attention mega-GEMM ==================
// T2 (chunk XOR swizzle) + T3/T4 (8-phase counted vmcnt) + T5 (setprio).
// 512 thr = 8 waves (2M x 4N), fragment-interleaved: wave's mfrag i -> rows
// i*32+wm*16, nfrag j -> cols j*64+wn*16, so quadrant (QM,QN) touches exactly
// A-half QM / B-half QN -> half-tile staging aligns with consumption.
// Per phase: {ds_read quad frags | stage 1 half-tile} vmcnt(4) barrier
//            lgkmcnt(0) setprio(1) 16 MFMA setprio(0) barrier.
// Stage order per tile t (into buf^1, for t+1): ph1 A0, ph2 B0, ph3 B1, ph4 A1.
// vmcnt(4) keeps 2 half-tiles in flight; steady state: each phase's 2 new loads
// push the FIFO to 6, so vmcnt(4) retires the 2 oldest = exactly the half-tile
// needed 1-2 phases later, always ahead of its first ds_read + barrier-published.
// LAST-TILE FIX: with pf=false no loads are issued, the FIFO sits at 4 and
// vmcnt(4) becomes a no-op -> phase-2/3 reads of the final B1/A1 would race the
// DMA. Drain vmcnt(0) once in the last iteration's phase 1 (uniform branch).
// LDS swizzle: 16B chunk index ch = (r*8 + cq) ^ (r&7) (involution). Staging
// writes linearly (global_load_lds) with pre-swizzled SOURCE column q_src =
// (l&7)^(l>>3); reads apply the same XOR (rule #21 both-sides).

__device__ __forceinline__ bf16x8 lds_frag(const short* buf, int r, int cq){
  int ch = (r*8 + cq) ^ (r&7);
  return *(const bf16x8*)(buf + ch*8);
}

__device__ __forceinline__ void stage_half(const short* __restrict__ src, int grow0, int K,
    short* ldsbuf, int half, int k0, int w, int l, int q_src){
  #pragma unroll
  for(int inst=0; inst<2; inst++){
    int r_local = half*128 + w*16 + inst*8;            // multiple of 8
    const short* g = src + (size_t)(grow0 + r_local + (l>>3))*K + k0 + q_src*8;
    async_copy16(ldsbuf + r_local*64, g);
  }
}

__device__ __forceinline__ void read_aquad(bf16x8 (&a)[4][2], const short* Ab, int rbase, int li, int qq){
  #pragma unroll
  for(int ii=0; ii<4; ii++)
    #pragma unroll
    for(int ks=0; ks<2; ks++)
      a[ii][ks] = lds_frag(Ab, rbase + ii*32 + li, ks*4 + qq);
}
__device__ __forceinline__ void read_bpair(bf16x8 (&b)[2][2], const short* Bb, int rbase, int li, int qq){
  #pragma unroll
  for(int jj=0; jj<2; jj++)
    #pragma unroll
    for(int ks=0; ks<2; ks++)
      b[jj][ks] = lds_frag(Bb, rbase + jj*64 + li, ks*4 + qq);
}
template<int QM, int QN>
__device__ __forceinline__ void mfma_quad(f32x4 (&acc)[8][4], const bf16x8 (&a)[4][2], const bf16x8 (&b)[2][2]){
  #pragma unroll
  for(int ii=0; ii<4; ii++)
    #pragma unroll
    for(int jj=0; jj<2; jj++)
      #pragma unroll
      for(int ks=0; ks<2; ks++)
        acc[QM*4+ii][QN*2+jj] =
          __builtin_amdgcn_mfma_f32_16x16x32_bf16(a[ii][ks], b[jj][ks], acc[QM*4+ii][QN*2+jj], 0, 0, 0);
}

#define PHASE_MID() do{ SB0(); asm volatile("s_waitcnt vmcnt(4)" ::: "memory"); SB0(); \
                        __builtin_amdgcn_s_barrier(); SB0(); }while(0)
#define LGKM0()     do{ asm volatile("s_waitcnt lgkmcnt(0)" ::: "memory"); SB0(); }while(0)
#define PHASE_END() do{ SB0(); __builtin_amdgcn_s_barrier(); SB0(); }while(0)

__global__ __launch_bounds__(512,2) void attn_gemm_8ph(const short* __restrict__ catT,
    const short* __restrict__ W1b, const float* __restrict__ b1, const float* __restrict__ W2,
    float* __restrict__ score_pre){
  extern __shared__ short lds[];
  short* AsB = lds;                    // [2][256][64]
  short* BsB = lds + 2*256*64;         // [2][256][64]
  const int K = NN;
  const int nkt = K/64;                // 128 K-tiles
  int id = blockIdx.x;                 // 0..191
  int cc = id&7, g = id>>3;            // XCD swizzle: 192 = 8 XCD x 24
  int m0 = (g%6)*256;
  int n0 = (cc*4 + g/6)*256;
  int tid = threadIdx.x;
  int w = tid>>6, l = tid&63;
  int wm = w>>2, wn = w&3;
  int li = l&15, qq = l>>4;
  int q_src = (l&7) ^ (l>>3);

  f32x4 acc[8][4];
  #pragma unroll
  for(int i=0;i<8;i++)
    #pragma unroll
    for(int j=0;j<4;j++) acc[i][j] = (f32x4){0.f,0.f,0.f,0.f};

  // prologue: stage tile 0 fully into buf 0, drain, publish
  stage_half(catT, m0, K, AsB, 0, 0, w, l, q_src);
  stage_half(catT, m0, K, AsB, 1, 0, w, l, q_src);
  stage_half(W1b,  n0, K, BsB, 0, 0, w, l, q_src);
  stage_half(W1b,  n0, K, BsB, 1, 0, w, l, q_src);
  SB0();
  asm volatile("s_waitcnt vmcnt(0)" ::: "memory");
  SB0();
  __builtin_amdgcn_s_barrier();
  SB0();

  bf16x8 a[4][2], b0[2][2], b1f[2][2];
  #pragma unroll 1
  for(int t=0; t<nkt; ++t){
    short* Ab = AsB + (t&1)*16384;
    short* Bb = BsB + (t&1)*16384;
    short* An = AsB + ((t&1)^1)*16384;
    short* Bn = BsB + ((t&1)^1)*16384;
    int k1 = (t+1)*64;
    bool pf = (t+1 < nkt);
    // ---- phase 1: quad(0,0) — read A-half0 frags + B-half0 frags; stage A0(t+1)
    read_aquad(a,  Ab, wm*16,        li, qq);
    read_bpair(b0, Bb, wn*16,        li, qq);
    if(pf) stage_half(catT, m0, K, An, 0, k1, w, l, q_src);
    else { SB0(); asm volatile("s_waitcnt vmcnt(0)" ::: "memory"); SB0(); }  // last-tile drain
    PHASE_MID();
    LGKM0();
    __builtin_amdgcn_s_setprio(1);
    mfma_quad<0,0>(acc, a, b0);
    __builtin_amdgcn_s_setprio(0);
    PHASE_END();
    // ---- phase 2: quad(0,1) — read B-half1 frags; stage B0(t+1)
    read_bpair(b1f, Bb, 128 + wn*16, li, qq);
    if(pf) stage_half(W1b, n0, K, Bn, 0, k1, w, l, q_src);
    PHASE_MID();
    LGKM0();
    __builtin_amdgcn_s_setprio(1);
    mfma_quad<0,1>(acc, a, b1f);
    __builtin_amdgcn_s_setprio(0);
    PHASE_END();
    // ---- phase 3: quad(1,1) — read A-half1 frags; stage B1(t+1)
    read_aquad(a, Ab, 128 + wm*16,   li, qq);
    if(pf) stage_half(W1b, n0, K, Bn, 1, k1, w, l, q_src);
    PHASE_MID();
    LGKM0();
    __builtin_amdgcn_s_setprio(1);
    mfma_quad<1,1>(acc, a, b1f);
    __builtin_amdgcn_s_setprio(0);
    PHASE_END();
    // ---- phase 4: quad(1,0) — no new reads (a=mh1, b0=nh0 live); stage A1(t+1)
    if(pf) stage_half(catT, m0, K, An, 1, k1, w, l, q_src);
    PHASE_MID();
    __builtin_amdgcn_s_setprio(1);
    mfma_quad<1,0>(acc, a, b0);
    __builtin_amdgcn_s_setprio(0);
    PHASE_END();
  }

  // epilogue: relu(C + b1) dot W2 over this block's 256 n-cols -> score_pre[m]
  float w2v[4], b1v[4];
  #pragma unroll
  for(int j=0;j<4;j++){ int gn = n0 + j*64 + wn*16 + li; w2v[j]=W2[gn]; b1v[j]=b1[gn]; }
  #pragma unroll
  for(int i=0;i<8;i++){
    #pragma unroll
    for(int rr=0;rr<4;rr++){
      float s=0.f;
      #pragma unroll
      for(int j=0;j<4;j++){
        float v = acc[i][j][rr] + b1v[j];
        v = v>0.f ? v : 0.f;
        s += v*w2v[j];
      }
      s += __shfl_xor(s,1); s += __shfl_xor(s,2); s += __shfl_xor(s,4); s += __shfl_xor(s,8);
      if(li==0) atomicAdd(&score_pre[m0 + i*32 + wm*16 + qq*4 + rr], s);
    }
  }
}

// fallback if ws can't hold W1b
__global__ __launch_bounds__(256) void attn_gemm_f32(const short* __restrict__ catT,
    const float* __restrict__ W1, const float* __restrict__ b1, const float* __restrict__ W2,
    float* __restrict__ score_pre){
  const int K = NN;
  int lane = threadIdx.x & 63;
  int wv   = threadIdx.x >> 6;
  int m0 = (blockIdx.x*4 + wv)*64;
  int n0 = blockIdx.y*64;
  int li = lane & 15, q = lane >> 4;
  const short* Ab = catT + (size_t)(m0+li)*K + q*8;
  const float* Bb = W1 + (size_t)(n0+li)*K + q*8;
  f32x4 acc[4][4];
  #pragma unroll
  for(int i=0;i<4;i++)
    #pragma unroll
    for(int j=0;j<4;j++) acc[i][j] = (f32x4){0.f,0.f,0.f,0.f};
  for(int k0=0;k0<K;k0+=32){
    bf16x8 a[4], b[4];
    #pragma unroll
    for(int i=0;i<4;i++) a[i] = *(const bf16x8*)(Ab + (size_t)i*16*K + k0);
    #pragma unroll
    for(int j=0;j<4;j++){
      const float* p = Bb + (size_t)j*16*K + k0;
      float4 f0 = *(const float4*)p;
      float4 f1 = *(const float4*)(p+4);
      bf16x8 t;
      t[0]=f2bf(f0.x); t[1]=f2bf(f0.y); t[2]=f2bf(f0.z); t[3]=f2bf(f0.w);
      t[4]=f2bf(f1.x); t[5]=f2bf(f1.y); t[6]=f2bf(f1.z); t[7]=f2bf(f1.w);
      b[j]=t;
    }
    #pragma unroll
    for(int i=0;i<4;i++)
      #pragma unroll
      for(int j=0;j<4;j++)
        acc[i][j] = __builtin_amdgcn_mfma_f32_16x16x32_bf16(a[i], b[j], acc[i][j], 0, 0, 0);
  }
  float w2v[4], b1v[4];
  #pragma unroll
  for(int j=0;j<4;j++){ int gn=n0+j*16+li; w2v[j]=W2[gn]; b1v[j]=b1[gn]; }
  #pragma unroll
  for(int i=0;i<4;i++){
    #pragma unroll
    for(int r=0;r<4;r++){
      float s=0.f;
      #pragma unroll
      for(int j=0;j<4;j++){
        float v = acc[i][j][r] + b1v[j];
        v = v>0.f ? v : 0.f;
        s += v*w2v[j];
      }
      s += __shfl_xor(s,1); s += __shfl_xor(s,2); s += __shfl_xor(s,4); s += __shfl_xor(s,8);
      if(li==0) atomicAdd(&score_pre[m0 + i*16 + q*4 + r], s);
    }
  }
}

// ---------------- score finalize ----------------
__global__ void k_score(const float* __restrict__ pre, const float* __restrict__ b2,
                        const float* __restrict__ center, const float* __restrict__ clsW,
                        float* __restrict__ sw){
  int d = blockIdx.x*256 + threadIdx.x;
  if(d>=DCATD) return;
  float sc = pre[d] + b2[0];
  sc = 1.f/(1.f+expf(-sc));
  sc -= center[d];
  #pragma unroll
  for(int o=0;o<10;o++) sw[d*10+o] = sc * clsW[(size_t)o*DCATD + d];
}

// ---------------- final ----------------
__global__ __launch_bounds__(64) void k_final(const float* __restrict__ x, const float* __restrict__ o1,
    const float* __restrict__ o2, const float* __restrict__ sw, const float* __restrict__ clsb,
    float* __restrict__ out){
  int i = blockIdx.x, l = threadIdx.x;
  float acc[10];
  #pragma unroll
  for(int o=0;o<10;o++) acc[o]=0.f;
  for(int d=l; d<DCATD; d+=64){
    float v = (d<FD) ? x[(size_t)i*FD + d]
            : (d<FD+HIDD) ? o1[(size_t)i*HIDD + d-FD]
            : o2[(size_t)i*HIDD + d-FD-HIDD];
    const float* s = sw + (size_t)d*10;
    #pragma unroll
    for(int o=0;o<10;o++) acc[o] += v*s[o];
  }
  #pragma unroll
  for(int o=0;o<10;o++){
    float t = acc[o];
    for(int off=32;off;off>>=1) t += __shfl_down(t,off);
    if(l==0) out[(size_t)i*10 + o] = t + clsb[o];
  }
}

extern "C" void kernel_launch(void* const* d_in, const int* in_sizes, int n_in,
                              void* d_out, int out_size, void* d_ws, size_t ws_size,
                              hipStream_t stream) {
  const float* x      = (const float*)d_in[0];
  const int*   ei     = (const int*)d_in[1];
  const float* eattr  = (const float*)d_in[2];
  const float* gn1_w  = (const float*)d_in[3];
  const float* gn1_b  = (const float*)d_in[4];
  const float* gn1_ms = (const float*)d_in[5];
  const float* gn2_w  = (const float*)d_in[6];
  const float* gn2_b  = (const float*)d_in[7];
  const float* gn2_ms = (const float*)d_in[8];
  const float* hg1_W  = (const float*)d_in[9];
  const float* hg1_att= (const float*)d_in[10];
  const float* hg1_b  = (const float*)d_in[11];
  const float* hg2_W  = (const float*)d_in[12];
  const float* hg2_att= (const float*)d_in[13];
  const float* hg2_b  = (const float*)d_in[14];
  const float* fc1_W  = (const float*)d_in[15];
  const float* fc1_b  = (const float*)d_in[16];
  const float* fc2_W  = (const float*)d_in[17];
  const float* fc2_b  = (const float*)d_in[18];
  const float* attn_W1= (const float*)d_in[19];
  const float* attn_b1= (const float*)d_in[20];
  const float* attn_W2= (const float*)d_in[21];
  const float* attn_b2= (const float*)d_in[22];
  const float* cls_W  = (const float*)d_in[23];
  const float* cls_b  = (const float*)d_in[24];
  const float* center = (const float*)d_in[25];
  float* out = (float*)d_out;

  const int* row = ei;
  const int* col = ei + NNZE;

  char* w = (char*)d_ws;
  size_t off = 0;
  auto alloc = [&](size_t bytes)->void*{
    off = (off + 255) & ~(size_t)255;
    void* p = w + off;
    off += bytes;
    return p;
  };
  float* xt    = (float*)alloc((size_t)NN*FD*4);     // used as bf16 (xtb)
  float* ef    = (float*)alloc((size_t)NN*FD*4);     // used as bf16 (efb); later catT
  float* h     = (float*)alloc((size_t)NN*FD*4);
  float* out1  = (float*)alloc((size_t)NN*HIDD*4);
  float* out2  = (float*)alloc((size_t)NN*HIDD*4);
  short* inb   = (short*)alloc((size_t)NN*FD*2);     // normalized bf16 (affdot out)
  short* hbf   = (short*)alloc((size_t)NN*FD*2);     // h bf16 (seg_gather dual out)
  short* wb1   = (short*)alloc((size_t)FD*FD*2);
  short* wb2   = (short*)alloc((size_t)FD*FD*2);
  short* fwb1  = (short*)alloc((size_t)HIDD*FD*2);
  short* fwb2  = (short*)alloc((size_t)HIDD*FD*2);
  int* cnt_col = (int*)alloc(NN*4);                  // adjacent to cnt_row (one memset)
  int* cnt_row = (int*)alloc(NN*4);
  int* col_off = (int*)alloc((NN+1)*4);
  int* row_off = (int*)alloc((NN+1)*4);
  int* col_cur = (int*)alloc(NN*4);
  int* row_cur = (int*)alloc(NN*4);
  int* ceids   = (int*)alloc(NNZE*4);
  int* reids   = (int*)alloc(NNZE*4);
  float* Bn    = (float*)alloc(NN*4);
  float* Dn    = (float*)alloc(NN*4);
  float* a_x   = (float*)alloc(NN*4);
  float* a_e   = (float*)alloc(NN*4);
  float* asm_  = (float*)alloc(NNZE*4);
  float* gsum  = (float*)alloc(FD*4);                // adjacent to gssq (one memset)
  float* gssq  = (float*)alloc(FD*4);
  float* gnA   = (float*)alloc(FD*4);
  float* gnB   = (float*)alloc(FD*4);
  float* wxr   = (float*)alloc(FD*4);
  float* we    = (float*)alloc(FD*4);
  float* score_pre = (float*)alloc(DCATD*4);
  float* sw    = (float*)alloc(DCATD*10*4);
  short* catT  = (short*)ef;   // alias: efb dead by the time catT is built
  short* xtb   = (short*)xt;   // bf16 xt (gemm_lds dual-out)
  short* efb   = (short*)ef;   // bf16 efeat (gather1 out)
  size_t off_before_w1b = off;
  short* W1b   = (short*)alloc((size_t)NN*NN*2);
  bool use_w1b = (off <= ws_size);
  if(!use_w1b) off = off_before_w1b;
  (void)n_in; (void)in_sizes; (void)out_size;

  // ---- CSR build (4 dispatches + 1 memset) ----
  hipMemsetAsync(cnt_col, 0, 2*NN*4, stream);        // covers cnt_col + cnt_row
  k_hist<<<NNZE/256, 256, 0, stream>>>(row, col, cnt_row, cnt_col);
  k_scan2<<<2, 1024, 0, stream>>>(cnt_col, cnt_row, col_off, row_off, col_cur, row_cur, Bn, Dn);
  k_scatter<<<NNZE/256, 256, 0, stream>>>(row, col, col_cur, row_cur, ceids, reids);

  // ---- all weight conversions in one dispatch ----
  int nW1 = use_w1b ? (int)((size_t)NN*NN/2048) : 0;   // 32768 or 0
  k_cvt_all<<<nW1 + 864, 256, 0, stream>>>(nW1, attn_W1, W1b,
      hg1_W, wb1, hg2_W, wb2, fc1_W, fwb1, fc2_W, fwb2);

  for(int layer=0; layer<2; layer++){
    const float* src_feat = (layer==0) ? x : h;
    const float* gW   = (layer==0) ? gn1_w  : gn2_w;
    const float* gB   = (layer==0) ? gn1_b  : gn2_b;
    const float* gMS  = (layer==0) ? gn1_ms : gn2_ms;
    const float* hgW  = (layer==0) ? hg1_W  : hg2_W;
    const float* hgAtt= (layer==0) ? hg1_att: hg2_att;
    const float* hgB  = (layer==0) ? hg1_b  : hg2_b;
    const short* wbL  = (layer==0) ? wb1    : wb2;
    const short* fwbL = (layer==0) ? fwb1   : fwb2;
    const float* fcB  = (layer==0) ? fc1_b  : fc2_b;
    float* fout       = (layer==0) ? out1   : out2;

    hipMemsetAsync(gsum, 0, 2*FD*4, stream);         // covers gsum + gssq
    k_colstats<<<dim3(3,32), 256, 0, stream>>>(src_feat, gsum, gssq);
    k_watt<<<FD, 256, 0, stream>>>(hgW, hgAtt, gsum, gssq, gW, gB, gMS, gnA, gnB, wxr, we);
    k_matvec<<<NN, 64, 0, stream>>>(eattr, we, a_e);
    k_affdot<<<NN, 256, 0, stream>>>(src_feat, gnA, gnB, wxr, inb, a_x);
    // xt produced directly in bf16 (only consumer is gather1)
    gemm_lds<<<dim3(FD/64, NN/128), 256, 0, stream>>>(inb, wbL, nullptr, xtb, NN, FD, FD, nullptr, 1.f);
    k_softmax_seg<<<NN/4, 256, 0, stream>>>(col_off, ceids, row, a_x, a_e, asm_);
    // gather1: bf16 src, bf16-only out (efeat)
    k_seg_gather<<<NN, 192, 0, stream>>>(xtb, col_off, ceids, row, asm_, Bn, nullptr, 1.f, nullptr, efb);
    // gather2: bf16 src, f32 h + bf16 hbf out
    k_seg_gather<<<NN, 192, 0, stream>>>(efb, row_off, reids, col, asm_, Dn, hgB, 0.01f, h, hbf);
    gemm_lds<<<dim3(HIDD/64, NN/128), 256, 0, stream>>>(hbf, fwbL, fout, nullptr, NN, HIDD, FD, fcB, 0.01f);
  }

  // ---- attention over cat = [x, out1, out2] ----
  k_build_catT<<<dim3(NN/32, DCATD/32), dim3(32,8), 0, stream>>>(x, out1, out2, catT);
  hipMemsetAsync(score_pre, 0, DCATD*4, stream);
  if(use_w1b){
    static bool attr_set = false;
    if(!attr_set){
      hipFuncSetAttribute(reinterpret_cast<const void*>(attn_gemm_8ph),
                          hipFuncAttributeMaxDynamicSharedMemorySize, 131072);
      attr_set = true;
    }
    attn_gemm_8ph<<<192, 512, 131072, stream>>>(catT, W1b, attn_b1, attn_W2, score_pre);
  } else {
    attn_gemm_f32<<<dim3(DCATD/256, NN/64), 256, 0, stream>>>(catT, attn_W1, attn_b1, attn_W2, score_pre);
  }
  k_score<<<DCATD/256, 256, 0, stream>>>(score_pre, attn_b2, center, cls_W, sw);
  k_final<<<NN, 64, 0, stream>>>(x, out1, out2, sw, cls_b, out);
}